// Round 1
// baseline (6415.394 us; speedup 1.0000x reference)
//
#include <hip/hip_runtime.h>
#include <math.h>

#define SCALE 0.08838834764831845f  // 1/sqrt(128)

constexpr int Bn = 4, Sn = 2048, En = 2048, Dhn = 128;
constexpr int Mrows = Bn * Sn;           // 8192
constexpr int BH = 64;                   // B*H
constexpr size_t QKV = (size_t)Mrows * En;  // 16777216 floats per projection

// ---------------- Projection GEMM: C[8192][2048] = X[8192][2048] @ W[2048][2048]
// 128x128 tile, BK=16, 256 threads, 8x8 per thread (rows/cols split {t*4, 64+t*4})
__global__ __launch_bounds__(256) void proj_gemm(const float* __restrict__ X,
                                                 const float* __restrict__ W,
                                                 float* __restrict__ C) {
  __shared__ float As[16][132];  // [k][m] transposed
  __shared__ float Bs[16][132];  // [k][n] natural
  const int bm = blockIdx.y * 128;
  const int bn = blockIdx.x * 128;
  const int tid = threadIdx.x;
  const int tA = tid >> 4;   // row group 0..15
  const int tB = tid & 15;   // col group 0..15
  float acc[8][8] = {};
  for (int k0 = 0; k0 < En; k0 += 16) {
    float4 xv[2], wv[2];
#pragma unroll
    for (int t = 0; t < 2; ++t) {
      int f = t * 256 + tid;
      int row = f >> 2, kq = (f & 3) << 2;
      xv[t] = *(const float4*)&X[(size_t)(bm + row) * En + k0 + kq];
      int wk = f >> 5, nq = (f & 31) << 2;
      wv[t] = *(const float4*)&W[(size_t)(k0 + wk) * En + bn + nq];
    }
    __syncthreads();
#pragma unroll
    for (int t = 0; t < 2; ++t) {
      int f = t * 256 + tid;
      int row = f >> 2, kq = (f & 3) << 2;
      As[kq + 0][row] = xv[t].x; As[kq + 1][row] = xv[t].y;
      As[kq + 2][row] = xv[t].z; As[kq + 3][row] = xv[t].w;
      int wk = f >> 5, nq = (f & 31) << 2;
      *(float4*)&Bs[wk][nq] = wv[t];
    }
    __syncthreads();
#pragma unroll
    for (int kk = 0; kk < 16; ++kk) {
      float a[8], b[8];
      *(float4*)(a)     = *(const float4*)&As[kk][tA * 4];
      *(float4*)(a + 4) = *(const float4*)&As[kk][64 + tA * 4];
      *(float4*)(b)     = *(const float4*)&Bs[kk][tB * 4];
      *(float4*)(b + 4) = *(const float4*)&Bs[kk][64 + tB * 4];
#pragma unroll
      for (int i = 0; i < 8; ++i)
#pragma unroll
        for (int j = 0; j < 8; ++j) acc[i][j] = fmaf(a[i], b[j], acc[i][j]);
    }
  }
#pragma unroll
  for (int i = 0; i < 8; ++i) {
    int row = bm + ((i < 4) ? (tA * 4 + i) : (64 + tA * 4 + (i - 4)));
    float4 v0 = make_float4(acc[i][0], acc[i][1], acc[i][2], acc[i][3]);
    float4 v1 = make_float4(acc[i][4], acc[i][5], acc[i][6], acc[i][7]);
    *(float4*)&C[(size_t)row * En + bn + tB * 4] = v0;
    *(float4*)&C[(size_t)row * En + bn + 64 + tB * 4] = v1;
  }
}

// ---------------- Column-softmax stats: per (bh, 64-k strip) compute m_k, Z_k
// (softmax over QUERY axis -> per-k-column max & sum of exp)
__global__ __launch_bounds__(256) void stats_kernel(const float* __restrict__ Q,
                                                    const float* __restrict__ K,
                                                    float* __restrict__ Mo,
                                                    float* __restrict__ Zo) {
  __shared__ float KsT[128][68];   // [d][k] transposed strip (persistent)
  __shared__ float Qs[128][36];    // [q][d-chunk of 32]
  __shared__ float part[16][68];
  __shared__ float mnew[64];
  const int bh = blockIdx.y;
  const int k0 = blockIdx.x * 64;
  const size_t base = (size_t)bh * (Sn * Dhn);
  const int tid = threadIdx.x;
#pragma unroll
  for (int t = 0; t < 8; ++t) {    // 64 k x 128 d transposed
    int f = t * 256 + tid;
    int kr = f >> 5;
    int dq = (f & 31) << 2;
    float4 v = *(const float4*)&K[base + (size_t)(k0 + kr) * Dhn + dq];
    KsT[dq + 0][kr] = v.x; KsT[dq + 1][kr] = v.y;
    KsT[dq + 2][kr] = v.z; KsT[dq + 3][kr] = v.w;
  }
  const int tA = tid >> 4;  // q group: rows tA + 16*i
  const int tB = tid & 15;  // k group: cols tB*4+j
  float m_run = -INFINITY, z_run = 0.f;   // live in tid<64 (col = tid)
  for (int q0 = 0; q0 < Sn; q0 += 128) {
    float s[8][4];
#pragma unroll
    for (int i = 0; i < 8; ++i)
#pragma unroll
      for (int j = 0; j < 4; ++j) s[i][j] = 0.f;
    for (int dc = 0; dc < 128; dc += 32) {
      __syncthreads();
#pragma unroll
      for (int t = 0; t < 4; ++t) {   // 128 q x 32 d
        int f = t * 256 + tid;
        int row = f >> 3;
        int dq = (f & 7) << 2;
        *(float4*)&Qs[row][dq] =
            *(const float4*)&Q[base + (size_t)(q0 + row) * Dhn + dc + dq];
      }
      __syncthreads();
#pragma unroll 8
      for (int dd = 0; dd < 32; ++dd) {
        float b[4];
        *(float4*)b = *(const float4*)&KsT[dc + dd][tB * 4];
#pragma unroll
        for (int i = 0; i < 8; ++i) {
          float a = Qs[tA + 16 * i][dd];
#pragma unroll
          for (int j = 0; j < 4; ++j) s[i][j] = fmaf(a, b[j], s[i][j]);
        }
      }
    }
    __syncthreads();
#pragma unroll
    for (int j = 0; j < 4; ++j) {
      float lm = -INFINITY;
#pragma unroll
      for (int i = 0; i < 8; ++i) lm = fmaxf(lm, s[i][j]);
      part[tA][tB * 4 + j] = lm * SCALE;
    }
    __syncthreads();
    float mn_local = 0.f;
    if (tid < 64) {
      float mt = -INFINITY;
#pragma unroll
      for (int t = 0; t < 16; ++t) mt = fmaxf(mt, part[t][tid]);
      mn_local = fmaxf(m_run, mt);
      mnew[tid] = mn_local;
    }
    __syncthreads();
#pragma unroll
    for (int j = 0; j < 4; ++j) {
      float mj = mnew[tB * 4 + j];
      float zp = 0.f;
#pragma unroll
      for (int i = 0; i < 8; ++i) zp += expf(s[i][j] * SCALE - mj);
      part[tA][tB * 4 + j] = zp;
    }
    __syncthreads();
    if (tid < 64) {
      float zt = 0.f;
#pragma unroll
      for (int t = 0; t < 16; ++t) zt += part[t][tid];
      z_run = z_run * expf(m_run - mn_local) + zt;
      m_run = mn_local;
    }
  }
  if (tid < 64) {
    Mo[bh * Sn + k0 + tid] = m_run;
    Zo[bh * Sn + k0 + tid] = z_run;
  }
}

// ---------------- Attention: per (bh, 32-q tile): O = P @ V with P = exp(s*scale - m_k)/Z_k
// Q lives in d_out (read fully at block start), O overwrites the same rows at the end.
__global__ __launch_bounds__(256) void attn_kernel(float* __restrict__ QO,
                                                   const float* __restrict__ K,
                                                   const float* __restrict__ V,
                                                   const float* __restrict__ Mo,
                                                   const float* __restrict__ Zo) {
  __shared__ float QsT[128][36];  // [d][q], 32 q rows
  __shared__ float KVs[64][132];  // K natural, then reused for V
  __shared__ float Ps[64][36];    // [k][q]
  const int bh = blockIdx.y;
  const int q0 = blockIdx.x * 32;
  const size_t base = (size_t)bh * (Sn * Dhn);
  const int tid = threadIdx.x;
#pragma unroll
  for (int t = 0; t < 4; ++t) {   // 32 q x 128 d transposed
    int f = t * 256 + tid;
    int row = f >> 5;
    int dq = (f & 31) << 2;
    float4 v = *(const float4*)&QO[base + (size_t)(q0 + row) * Dhn + dq];
    QsT[dq + 0][row] = v.x; QsT[dq + 1][row] = v.y;
    QsT[dq + 2][row] = v.z; QsT[dq + 3][row] = v.w;
  }
  const int tA = tid >> 4;   // score: k rows tA*4+i
  const int tB = tid & 15;   // score: q cols tB*2+j
  const int tQ = tid >> 5;   // PV: q rows tQ*4+i
  const int tD = tid & 31;   // PV: d cols tD + 32*j
  float acc[4][4] = {};
  for (int kt = 0; kt < Sn; kt += 64) {
    __syncthreads();
#pragma unroll
    for (int t = 0; t < 8; ++t) {   // stage K (natural)
      int f = t * 256 + tid;
      int kr = f >> 5;
      int dq = (f & 31) << 2;
      *(float4*)&KVs[kr][dq] = *(const float4*)&K[base + (size_t)(kt + kr) * Dhn + dq];
    }
    float mk[4], rz[4];
#pragma unroll
    for (int i = 0; i < 4; ++i) {
      mk[i] = Mo[bh * Sn + kt + tA * 4 + i];
      rz[i] = 1.f / Zo[bh * Sn + kt + tA * 4 + i];
    }
    __syncthreads();
    float s[4][2] = {};
#pragma unroll 4
    for (int dd = 0; dd < 128; ++dd) {
      float a[4];
#pragma unroll
      for (int i = 0; i < 4; ++i) a[i] = KVs[tA * 4 + i][dd];
      float b0 = QsT[dd][tB * 2 + 0];
      float b1 = QsT[dd][tB * 2 + 1];
#pragma unroll
      for (int i = 0; i < 4; ++i) {
        s[i][0] = fmaf(a[i], b0, s[i][0]);
        s[i][1] = fmaf(a[i], b1, s[i][1]);
      }
    }
#pragma unroll
    for (int i = 0; i < 4; ++i)
#pragma unroll
      for (int j = 0; j < 2; ++j)
        Ps[tA * 4 + i][tB * 2 + j] = expf(s[i][j] * SCALE - mk[i]) * rz[i];
    __syncthreads();   // K reads + P writes complete
#pragma unroll
    for (int t = 0; t < 8; ++t) {   // stage V over K's buffer
      int f = t * 256 + tid;
      int kr = f >> 5;
      int dq = (f & 31) << 2;
      *(float4*)&KVs[kr][dq] = *(const float4*)&V[base + (size_t)(kt + kr) * Dhn + dq];
    }
    __syncthreads();
#pragma unroll 8
    for (int kk = 0; kk < 64; ++kk) {
      float pa[4];
      *(float4*)pa = *(const float4*)&Ps[kk][tQ * 4];
      float vb[4];
#pragma unroll
      for (int j = 0; j < 4; ++j) vb[j] = KVs[kk][tD + 32 * j];
#pragma unroll
      for (int i = 0; i < 4; ++i)
#pragma unroll
        for (int j = 0; j < 4; ++j) acc[i][j] = fmaf(pa[i], vb[j], acc[i][j]);
    }
  }
#pragma unroll
  for (int i = 0; i < 4; ++i)
#pragma unroll
    for (int j = 0; j < 4; ++j)
      QO[base + (size_t)(q0 + tQ * 4 + i) * Dhn + tD + 32 * j] = acc[i][j];
}

extern "C" void kernel_launch(void* const* d_in, const int* in_sizes, int n_in,
                              void* d_out, int out_size, void* d_ws, size_t ws_size,
                              hipStream_t stream) {
  (void)in_sizes; (void)n_in; (void)out_size; (void)ws_size;
  const float* x  = (const float*)d_in[0];
  const float* wq = (const float*)d_in[1];
  const float* wk = (const float*)d_in[2];
  const float* wv = (const float*)d_in[3];
  float* out = (float*)d_out;
  float* ws  = (float*)d_ws;
  float* Kp = ws;                    // 64 MB
  float* Vp = ws + QKV;              // 64 MB
  float* Mp = ws + 2 * QKV;          // 0.5 MB
  float* Zp = Mp + (size_t)BH * Sn;  // 0.5 MB
  dim3 blk(256);
  proj_gemm<<<dim3(16, 64), blk, 0, stream>>>(x, wq, out);  // Q -> d_out
  proj_gemm<<<dim3(16, 64), blk, 0, stream>>>(x, wk, Kp);
  proj_gemm<<<dim3(16, 64), blk, 0, stream>>>(x, wv, Vp);
  stats_kernel<<<dim3(32, 64), blk, 0, stream>>>(out, Kp, Mp, Zp);
  attn_kernel<<<dim3(64, 64), blk, 0, stream>>>(out, Kp, Vp, Mp, Zp);
}

// Round 2
// 2692.204 us; speedup vs baseline: 2.3830x; 2.3830x over previous
//
#include <hip/hip_runtime.h>
#include <math.h>

typedef _Float16 half_t;
typedef __attribute__((ext_vector_type(8))) _Float16 f16x8;
typedef __attribute__((ext_vector_type(4))) _Float16 f16x4;
typedef __attribute__((ext_vector_type(4))) float f32x4;

#define MFMA __builtin_amdgcn_mfma_f32_16x16x32_f16
#define K1C (0.08838834764831845f * 1.4426950408889634f)  // SCALE * log2(e)
#define RLO (1.0f / 2048.0f)

// async global->LDS, 16B per lane (linear dest = base + lane*16)
__device__ inline void gld16(const void* g, void* l) {
  __builtin_amdgcn_global_load_lds(
      (const __attribute__((address_space(1))) uint32_t*)g,
      (__attribute__((address_space(3))) uint32_t*)l, 16, 0, 0);
}

// ---------- split fp32 -> fp16 hi + fp16 lo*2^11 ----------
__global__ __launch_bounds__(256) void split_x(const float* __restrict__ X,
                                               half_t* __restrict__ Xh,
                                               half_t* __restrict__ Xl) {
  size_t i = (size_t)blockIdx.x * 256 + threadIdx.x;
  const size_t stride = (size_t)gridDim.x * 256;
  for (size_t p = i; p < 4194304; p += stride) {
    f32x4 v = ((const f32x4*)X)[p];
    f16x4 h, l;
#pragma unroll
    for (int j = 0; j < 4; ++j) {
      half_t hh = (half_t)v[j];
      h[j] = hh;
      l[j] = (half_t)((v[j] - (float)hh) * 2048.0f);
    }
    ((f16x4*)Xh)[p] = h;
    ((f16x4*)Xl)[p] = l;
  }
}

// ---------- W[2048][2048] -> Wt[n][k] split halves ----------
__global__ __launch_bounds__(256) void wtrans_split(const float* __restrict__ W,
                                                    half_t* __restrict__ Wh,
                                                    half_t* __restrict__ Wl) {
  __shared__ float T[64][68];
  const int tid = threadIdx.x;
  const int k0 = blockIdx.x * 64, n0 = blockIdx.y * 64;
#pragma unroll
  for (int t = 0; t < 4; ++t) {
    int s = t * 256 + tid;
    int kr = s >> 4, nc = (s & 15) * 4;
    f32x4 v = *(const f32x4*)&W[(size_t)(k0 + kr) * 2048 + n0 + nc];
#pragma unroll
    for (int j = 0; j < 4; ++j) T[nc + j][kr] = v[j];
  }
  __syncthreads();
#pragma unroll
  for (int t = 0; t < 4; ++t) {
    int s = t * 256 + tid;
    int nr = s >> 4, kc = (s & 15) * 4;
    f16x4 h, l;
#pragma unroll
    for (int j = 0; j < 4; ++j) {
      float q = T[nr][kc + j];
      half_t hh = (half_t)q;
      h[j] = hh;
      l[j] = (half_t)((q - (float)hh) * 2048.0f);
    }
    *(f16x4*)&Wh[(size_t)(n0 + nr) * 2048 + k0 + kc] = h;
    *(f16x4*)&Wl[(size_t)(n0 + nr) * 2048 + k0 + kc] = l;
  }
}

// ---------- projection GEMM: C[m][n] = sum_k X[m][k]*Wt[n][k], split-fp16 MFMA
// 128x128 tile, BK=64, 4 waves (each 64x64), XOR-swizzled LDS (src-side pre-swizzle)
__global__ __launch_bounds__(256) void proj_mfma(
    const half_t* __restrict__ Xh, const half_t* __restrict__ Xl,
    const half_t* __restrict__ Wh, const half_t* __restrict__ Wl,
    half_t* __restrict__ Ch, half_t* __restrict__ Cl, const int mode) {
  __shared__ half_t sAh[8192], sAl[8192], sBh[8192], sBl[8192];
  const int tid = threadIdx.x;
  const int m0 = blockIdx.y << 7, n0 = blockIdx.x << 7;
  const int w = tid >> 6, lane = tid & 63, c = lane & 15, g = lane >> 4;
  const int wr = w >> 1, wc = w & 1;
  f32x4 z4 = {0.f, 0.f, 0.f, 0.f};
  f32x4 acc0[4][4], accX[4][4];
#pragma unroll
  for (int i = 0; i < 4; ++i)
#pragma unroll
    for (int j = 0; j < 4; ++j) { acc0[i][j] = z4; accX[i][j] = z4; }
  for (int k0 = 0; k0 < 2048; k0 += 64) {
#pragma unroll
    for (int t = 0; t < 4; ++t) {
      int s = t * 256 + tid;
      int row = s >> 3;
      int lch = (s & 7) ^ (row & 7);  // pre-swizzled source chunk
      size_t ga = (size_t)(m0 + row) * 2048 + k0 + lch * 8;
      size_t gb = (size_t)(n0 + row) * 2048 + k0 + lch * 8;
      gld16(&Xh[ga], &sAh[s * 8]);
      gld16(&Xl[ga], &sAl[s * 8]);
      gld16(&Wh[gb], &sBh[s * 8]);
      gld16(&Wl[gb], &sBl[s * 8]);
    }
    __syncthreads();
#pragma unroll
    for (int ks = 0; ks < 2; ++ks) {
      f16x8 a0[4], a1[4], b0[4], b1[4];
#pragma unroll
      for (int i = 0; i < 4; ++i) {
        int ar = wr * 64 + i * 16 + c;
        int ap = ((ks << 2) | g) ^ (ar & 7);
        a0[i] = *(const f16x8*)&sAh[ar * 64 + ap * 8];
        a1[i] = *(const f16x8*)&sAl[ar * 64 + ap * 8];
        int br = wc * 64 + i * 16 + c;
        int bp = ((ks << 2) | g) ^ (br & 7);
        b0[i] = *(const f16x8*)&sBh[br * 64 + bp * 8];
        b1[i] = *(const f16x8*)&sBl[br * 64 + bp * 8];
      }
#pragma unroll
      for (int i = 0; i < 4; ++i)
#pragma unroll
        for (int j = 0; j < 4; ++j) {
          acc0[i][j] = MFMA(a0[i], b0[j], acc0[i][j], 0, 0, 0);
          if (mode == 0) {
            accX[i][j] = MFMA(a0[i], b1[j], accX[i][j], 0, 0, 0);
            accX[i][j] = MFMA(a1[i], b0[j], accX[i][j], 0, 0, 0);
          }
        }
    }
    __syncthreads();
  }
#pragma unroll
  for (int i = 0; i < 4; ++i)
#pragma unroll
    for (int j = 0; j < 4; ++j) {
      int mbase = m0 + wr * 64 + i * 16 + g * 4;
      int n = n0 + wc * 64 + j * 16 + c;
#pragma unroll
      for (int r = 0; r < 4; ++r) {
        float q = acc0[i][j][r] + accX[i][j][r] * RLO;
        half_t hh = (half_t)q;
        size_t o = (size_t)(mbase + r) * 2048 + n;
        Ch[o] = hh;
        if (mode == 0) Cl[o] = (half_t)((q - (float)hh) * 2048.0f);
      }
    }
}

// ---------- V[bh][k][d] -> Vt[bh][d][k], chunk-XOR-swizzled LDS transpose ----------
__global__ __launch_bounds__(256) void transpose_v(const half_t* __restrict__ V,
                                                   half_t* __restrict__ Vt) {
  __shared__ half_t T[128 * 128];
  const int tid = threadIdx.x;
  const int bh = blockIdx.y, k0 = blockIdx.x * 128;
  const size_t base = (size_t)bh << 18;
#pragma unroll
  for (int t = 0; t < 8; ++t) {
    int s = t * 256 + tid;
    int kr = s >> 4, ch = s & 15;
    int pc = ch ^ ((kr >> 3) & 15);
    *(f16x8*)&T[kr * 128 + pc * 8] =
        *(const f16x8*)&V[base + (size_t)(k0 + kr) * 128 + ch * 8];
  }
  __syncthreads();
#pragma unroll
  for (int t = 0; t < 8; ++t) {
    int s = t * 256 + tid;
    int d = s >> 4, kc = s & 15;
    f16x8 o;
#pragma unroll
    for (int j = 0; j < 8; ++j) {
      int kr = kc * 8 + j;
      int pc = (d >> 3) ^ (kc & 15);
      o[j] = T[kr * 128 + pc * 8 + (d & 7)];
    }
    *(f16x8*)&Vt[base + (size_t)d * 2048 + k0 + kc * 8] = o;
  }
}

// ---------- column-softmax stats: C2[k] = m_k + log2(z_k), scores in log2 domain
__global__ __launch_bounds__(256) void stats_mfma(
    const half_t* __restrict__ Qh, const half_t* __restrict__ Ql,
    const half_t* __restrict__ Kh, const half_t* __restrict__ Kl,
    float* __restrict__ C2) {
  const int tid = threadIdx.x;
  const int w = tid >> 6, lane = tid & 63, c = lane & 15, g = lane >> 4;
  const int bh = blockIdx.y;
  const size_t base = (size_t)bh << 18;
  const int kb = blockIdx.x * 128 + w * 32;
  f16x8 ka0[2][4], ka1[2][4];
#pragma unroll
  for (int kt = 0; kt < 2; ++kt)
#pragma unroll
    for (int ds = 0; ds < 4; ++ds) {
      size_t a = base + (size_t)(kb + kt * 16 + c) * 128 + ds * 32 + g * 8;
      ka0[kt][ds] = *(const f16x8*)&Kh[a];
      ka1[kt][ds] = *(const f16x8*)&Kl[a];
    }
  float m[2][4], z[2][4];
#pragma unroll
  for (int kt = 0; kt < 2; ++kt)
#pragma unroll
    for (int r = 0; r < 4; ++r) { m[kt][r] = -INFINITY; z[kt][r] = 0.f; }
  for (int q0 = 0; q0 < 2048; q0 += 16) {
    f16x8 qb0[4], qb1[4];
#pragma unroll
    for (int ds = 0; ds < 4; ++ds) {
      size_t a = base + (size_t)(q0 + c) * 128 + ds * 32 + g * 8;
      qb0[ds] = *(const f16x8*)&Qh[a];
      qb1[ds] = *(const f16x8*)&Ql[a];
    }
#pragma unroll
    for (int kt = 0; kt < 2; ++kt) {
      f32x4 A0 = {0.f, 0.f, 0.f, 0.f}, AX = {0.f, 0.f, 0.f, 0.f};
#pragma unroll
      for (int ds = 0; ds < 4; ++ds) {
        A0 = MFMA(ka0[kt][ds], qb0[ds], A0, 0, 0, 0);
        AX = MFMA(ka0[kt][ds], qb1[ds], AX, 0, 0, 0);
        AX = MFMA(ka1[kt][ds], qb0[ds], AX, 0, 0, 0);
      }
#pragma unroll
      for (int r = 0; r < 4; ++r) {
        float t = (A0[r] + AX[r] * RLO) * K1C;
        float mo = m[kt][r];
        float mn = fmaxf(mo, t);
        float e = __builtin_amdgcn_exp2f(fminf(mo, t) - mn);
        z[kt][r] = (t <= mo) ? (z[kt][r] + e) : (z[kt][r] * e + 1.0f);
        m[kt][r] = mn;
      }
    }
  }
#pragma unroll
  for (int mask = 1; mask < 16; mask <<= 1)
#pragma unroll
    for (int kt = 0; kt < 2; ++kt)
#pragma unroll
      for (int r = 0; r < 4; ++r) {
        float mo = __shfl_xor(m[kt][r], mask, 64);
        float zo = __shfl_xor(z[kt][r], mask, 64);
        float mn = fmaxf(m[kt][r], mo);
        z[kt][r] = z[kt][r] * __builtin_amdgcn_exp2f(m[kt][r] - mn) +
                   zo * __builtin_amdgcn_exp2f(mo - mn);
        m[kt][r] = mn;
      }
  if (c == 0) {
#pragma unroll
    for (int kt = 0; kt < 2; ++kt)
#pragma unroll
      for (int r = 0; r < 4; ++r)
        C2[(bh << 11) + kb + kt * 16 + g * 4 + r] =
            m[kt][r] + __builtin_amdgcn_logf(z[kt][r]);
  }
}

// ---------- attention: scores recompute, P = 2^(t - C2_k), O = P@V ----------
__global__ __launch_bounds__(256) void attn_mfma(
    const half_t* __restrict__ Qh, const half_t* __restrict__ Ql,
    const half_t* __restrict__ Kh, const half_t* __restrict__ Kl,
    const half_t* __restrict__ Vt, const float* __restrict__ C2,
    float* __restrict__ O) {
  __shared__ half_t P[4][16][40];  // wave-private, 80B row pitch (16B aligned)
  const int tid = threadIdx.x;
  const int w = tid >> 6, lane = tid & 63, c = lane & 15, g = lane >> 4;
  const int bh = blockIdx.y;
  const size_t base = (size_t)bh << 18;
  const int qb = blockIdx.x * 64 + w * 16;
  f32x4 z4 = {0.f, 0.f, 0.f, 0.f};
  f16x8 qf0[4], qf1[4];
#pragma unroll
  for (int ds = 0; ds < 4; ++ds) {
    size_t a = base + (size_t)(qb + c) * 128 + ds * 32 + g * 8;
    qf0[ds] = *(const f16x8*)&Qh[a];
    qf1[ds] = *(const f16x8*)&Ql[a];
  }
  f32x4 Oacc[8];
#pragma unroll
  for (int dt = 0; dt < 8; ++dt) Oacc[dt] = z4;
  for (int kt = 0; kt < 2048; kt += 32) {
#pragma unroll
    for (int h = 0; h < 2; ++h) {
      const int krow = kt + h * 16;
      f32x4 A0 = z4, AX = z4;
#pragma unroll
      for (int ds = 0; ds < 4; ++ds) {
        size_t a = base + (size_t)(krow + c) * 128 + ds * 32 + g * 8;
        f16x8 k0v = *(const f16x8*)&Kh[a];
        f16x8 k1v = *(const f16x8*)&Kl[a];
        A0 = MFMA(k0v, qf0[ds], A0, 0, 0, 0);
        AX = MFMA(k0v, qf1[ds], AX, 0, 0, 0);
        AX = MFMA(k1v, qf0[ds], AX, 0, 0, 0);
      }
      f32x4 c2v = *(const f32x4*)&C2[(bh << 11) + krow + g * 4];
      f16x4 pv;
#pragma unroll
      for (int r = 0; r < 4; ++r) {
        float t = (A0[r] + AX[r] * RLO) * K1C;
        pv[r] = (half_t)__builtin_amdgcn_exp2f(t - c2v[r]);
      }
      *(f16x4*)&P[w][c][h * 16 + g * 4] = pv;
    }
    f16x8 pa = *(const f16x8*)&P[w][c][g * 8];
#pragma unroll
    for (int dt = 0; dt < 8; ++dt) {
      f16x8 vb = *(const f16x8*)&Vt[base + (size_t)(dt * 16 + c) * 2048 + kt + g * 8];
      Oacc[dt] = MFMA(pa, vb, Oacc[dt], 0, 0, 0);
    }
  }
#pragma unroll
  for (int dt = 0; dt < 8; ++dt)
#pragma unroll
    for (int r = 0; r < 4; ++r)
      O[base + (size_t)(qb + g * 4 + r) * 128 + dt * 16 + c] = Oacc[dt][r];
}

extern "C" void kernel_launch(void* const* d_in, const int* in_sizes, int n_in,
                              void* d_out, int out_size, void* d_ws, size_t ws_size,
                              hipStream_t stream) {
  (void)in_sizes; (void)n_in; (void)out_size; (void)ws_size;
  const float* x = (const float*)d_in[0];
  const float* wq = (const float*)d_in[1];
  const float* wk = (const float*)d_in[2];
  const float* wv = (const float*)d_in[3];
  float* out = (float*)d_out;
  char* ws = (char*)d_ws;
  const size_t S2 = 33554432;  // bytes of one fp16 split [8192][2048]
  half_t* Wth = (half_t*)ws;
  half_t* Wtl = (half_t*)(ws + 8388608);
  half_t* Qh = (half_t*)(ws + 16777216);
  half_t* Ql = (half_t*)(ws + 16777216 + S2);
  half_t* Kh = (half_t*)(ws + 16777216 + 2 * S2);
  half_t* Kl = (half_t*)(ws + 16777216 + 3 * S2);
  half_t* Vh = (half_t*)(ws + 16777216 + 4 * S2);
  half_t* Vth = (half_t*)(ws + 16777216 + 5 * S2);
  float* C2 = (float*)(ws + 16777216 + 6 * S2);
  // X splits live in d_out (exactly 64 MB); dead before attn overwrites with O
  half_t* Xh = (half_t*)d_out;
  half_t* Xl = (half_t*)((char*)d_out + S2);
  dim3 b(256);
  split_x<<<2048, b, 0, stream>>>(x, Xh, Xl);
  wtrans_split<<<dim3(32, 32), b, 0, stream>>>(wq, Wth, Wtl);
  proj_mfma<<<dim3(16, 64), b, 0, stream>>>(Xh, Xl, Wth, Wtl, Qh, Ql, 0);
  wtrans_split<<<dim3(32, 32), b, 0, stream>>>(wk, Wth, Wtl);
  proj_mfma<<<dim3(16, 64), b, 0, stream>>>(Xh, Xl, Wth, Wtl, Kh, Kl, 0);
  wtrans_split<<<dim3(32, 32), b, 0, stream>>>(wv, Wth, Wtl);
  proj_mfma<<<dim3(16, 64), b, 0, stream>>>(Xh, Xl, Wth, Wtl, Vh, nullptr, 1);
  transpose_v<<<dim3(16, 64), b, 0, stream>>>(Vh, Vth);
  stats_mfma<<<dim3(16, 64), b, 0, stream>>>(Qh, Ql, Kh, Kl, C2);
  attn_mfma<<<dim3(32, 64), b, 0, stream>>>(Qh, Ql, Kh, Kl, Vth, C2, out);
}

// Round 4
// 1281.092 us; speedup vs baseline: 5.0078x; 2.1015x over previous
//
#include <hip/hip_runtime.h>
#include <math.h>

typedef _Float16 half_t;
typedef __attribute__((ext_vector_type(8))) _Float16 f16x8;
typedef __attribute__((ext_vector_type(4))) _Float16 f16x4;
typedef __attribute__((ext_vector_type(4))) float f32x4;

#define MFMA __builtin_amdgcn_mfma_f32_16x16x32_f16
#define K1C (0.08838834764831845f * 1.4426950408889634f)  // SCALE * log2(e)
#define RLO (1.0f / 2048.0f)

// async global->LDS, 16B per lane (linear dest = base + lane*16)
__device__ inline void gld16(const void* g, void* l) {
  __builtin_amdgcn_global_load_lds(
      (const __attribute__((address_space(1))) uint32_t*)g,
      (__attribute__((address_space(3))) uint32_t*)l, 16, 0, 0);
}

// ---------- split fp32 -> fp16 hi + fp16 lo*2^11 ----------
__global__ __launch_bounds__(256) void split_x(const float* __restrict__ X,
                                               half_t* __restrict__ Xh,
                                               half_t* __restrict__ Xl) {
  size_t i = (size_t)blockIdx.x * 256 + threadIdx.x;
  const size_t stride = (size_t)gridDim.x * 256;
  for (size_t p = i; p < 4194304; p += stride) {
    f32x4 v = ((const f32x4*)X)[p];
    f16x4 h, l;
#pragma unroll
    for (int j = 0; j < 4; ++j) {
      half_t hh = (half_t)v[j];
      h[j] = hh;
      l[j] = (half_t)((v[j] - (float)hh) * 2048.0f);
    }
    ((f16x4*)Xh)[p] = h;
    ((f16x4*)Xl)[p] = l;
  }
}

// ---------- W[2048][2048] -> Wt[n][k] split halves ----------
__global__ __launch_bounds__(256) void wtrans_split(const float* __restrict__ W,
                                                    half_t* __restrict__ Wh,
                                                    half_t* __restrict__ Wl) {
  __shared__ float T[64][68];
  const int tid = threadIdx.x;
  const int k0 = blockIdx.x * 64, n0 = blockIdx.y * 64;
#pragma unroll
  for (int t = 0; t < 4; ++t) {
    int s = t * 256 + tid;
    int kr = s >> 4, nc = (s & 15) * 4;
    f32x4 v = *(const f32x4*)&W[(size_t)(k0 + kr) * 2048 + n0 + nc];
#pragma unroll
    for (int j = 0; j < 4; ++j) T[nc + j][kr] = v[j];
  }
  __syncthreads();
#pragma unroll
  for (int t = 0; t < 4; ++t) {
    int s = t * 256 + tid;
    int nr = s >> 4, kc = (s & 15) * 4;
    f16x4 h, l;
#pragma unroll
    for (int j = 0; j < 4; ++j) {
      float q = T[nr][kc + j];
      half_t hh = (half_t)q;
      h[j] = hh;
      l[j] = (half_t)((q - (float)hh) * 2048.0f);
    }
    *(f16x4*)&Wh[(size_t)(n0 + nr) * 2048 + k0 + kc] = h;
    *(f16x4*)&Wl[(size_t)(n0 + nr) * 2048 + k0 + kc] = l;
  }
}

// ---------- projection GEMM: C[m][n] = sum_k X[m][k]*Wt[n][k], split-fp16 MFMA
__global__ __launch_bounds__(256) void proj_mfma(
    const half_t* __restrict__ Xh, const half_t* __restrict__ Xl,
    const half_t* __restrict__ Wh, const half_t* __restrict__ Wl,
    half_t* __restrict__ Ch, half_t* __restrict__ Cl, const int mode) {
  __shared__ half_t sAh[8192], sAl[8192], sBh[8192], sBl[8192];
  const int tid = threadIdx.x;
  const int m0 = blockIdx.y << 7, n0 = blockIdx.x << 7;
  const int w = tid >> 6, lane = tid & 63, c = lane & 15, g = lane >> 4;
  const int wr = w >> 1, wc = w & 1;
  f32x4 z4 = {0.f, 0.f, 0.f, 0.f};
  f32x4 acc0[4][4], accX[4][4];
#pragma unroll
  for (int i = 0; i < 4; ++i)
#pragma unroll
    for (int j = 0; j < 4; ++j) { acc0[i][j] = z4; accX[i][j] = z4; }
  for (int k0 = 0; k0 < 2048; k0 += 64) {
#pragma unroll
    for (int t = 0; t < 4; ++t) {
      int s = t * 256 + tid;
      int row = s >> 3;
      int lch = (s & 7) ^ (row & 7);  // pre-swizzled source chunk
      size_t ga = (size_t)(m0 + row) * 2048 + k0 + lch * 8;
      size_t gb = (size_t)(n0 + row) * 2048 + k0 + lch * 8;
      gld16(&Xh[ga], &sAh[s * 8]);
      gld16(&Xl[ga], &sAl[s * 8]);
      gld16(&Wh[gb], &sBh[s * 8]);
      gld16(&Wl[gb], &sBl[s * 8]);
    }
    __syncthreads();
#pragma unroll
    for (int ks = 0; ks < 2; ++ks) {
      f16x8 a0[4], a1[4], b0[4], b1[4];
#pragma unroll
      for (int i = 0; i < 4; ++i) {
        int ar = wr * 64 + i * 16 + c;
        int ap = ((ks << 2) | g) ^ (ar & 7);
        a0[i] = *(const f16x8*)&sAh[ar * 64 + ap * 8];
        a1[i] = *(const f16x8*)&sAl[ar * 64 + ap * 8];
        int br = wc * 64 + i * 16 + c;
        int bp = ((ks << 2) | g) ^ (br & 7);
        b0[i] = *(const f16x8*)&sBh[br * 64 + bp * 8];
        b1[i] = *(const f16x8*)&sBl[br * 64 + bp * 8];
      }
#pragma unroll
      for (int i = 0; i < 4; ++i)
#pragma unroll
        for (int j = 0; j < 4; ++j) {
          acc0[i][j] = MFMA(a0[i], b0[j], acc0[i][j], 0, 0, 0);
          if (mode == 0) {
            accX[i][j] = MFMA(a0[i], b1[j], accX[i][j], 0, 0, 0);
            accX[i][j] = MFMA(a1[i], b0[j], accX[i][j], 0, 0, 0);
          }
        }
    }
    __syncthreads();
  }
#pragma unroll
  for (int i = 0; i < 4; ++i)
#pragma unroll
    for (int j = 0; j < 4; ++j) {
      int mbase = m0 + wr * 64 + i * 16 + g * 4;
      int n = n0 + wc * 64 + j * 16 + c;
#pragma unroll
      for (int r = 0; r < 4; ++r) {
        float q = acc0[i][j][r] + accX[i][j][r] * RLO;
        half_t hh = (half_t)q;
        size_t o = (size_t)(mbase + r) * 2048 + n;
        Ch[o] = hh;
        if (mode == 0) Cl[o] = (half_t)((q - (float)hh) * 2048.0f);
      }
    }
}

// ---------- V[bh][k][d] -> Vt[bh][d][k] ----------
__global__ __launch_bounds__(256) void transpose_v(const half_t* __restrict__ V,
                                                   half_t* __restrict__ Vt) {
  __shared__ half_t T[128 * 128];
  const int tid = threadIdx.x;
  const int bh = blockIdx.y, k0 = blockIdx.x * 128;
  const size_t base = (size_t)bh << 18;
#pragma unroll
  for (int t = 0; t < 8; ++t) {
    int s = t * 256 + tid;
    int kr = s >> 4, ch = s & 15;
    int pc = ch ^ ((kr >> 3) & 15);
    *(f16x8*)&T[kr * 128 + pc * 8] =
        *(const f16x8*)&V[base + (size_t)(k0 + kr) * 128 + ch * 8];
  }
  __syncthreads();
#pragma unroll
  for (int t = 0; t < 8; ++t) {
    int s = t * 256 + tid;
    int d = s >> 4, kc = s & 15;
    f16x8 o;
#pragma unroll
    for (int j = 0; j < 8; ++j) {
      int kr = kc * 8 + j;
      int pc = (d >> 3) ^ (kc & 15);
      o[j] = T[kr * 128 + pc * 8 + (d & 7)];
    }
    *(f16x8*)&Vt[base + (size_t)d * 2048 + k0 + kc * 8] = o;
  }
}

// ---------- column-softmax stats: C2[k] = m_k + log2(z_k) ----------
// 4 waves x 32 k each; Q (hi+lo) staged in LDS double-buffered, shared.
#define STAGE_Q(nb, qn) do {                                                  \
    int r0_ = tid >> 4, cl0_ = tid & 15;                                      \
    size_t o0_ = base + (size_t)((qn) + r0_) * 128 + ((cl0_ ^ r0_) << 3);     \
    gld16(&Qh[o0_], &sQ0[nb][tid << 3]);                                      \
    gld16(&Ql[o0_], &sQ1[nb][tid << 3]);                                      \
    int r1_ = 16 + r0_;                                                       \
    size_t o1_ = base + (size_t)((qn) + r1_) * 128 + ((cl0_ ^ (r1_ & 15)) << 3); \
    gld16(&Qh[o1_], &sQ0[nb][(256 + tid) << 3]);                              \
    gld16(&Ql[o1_], &sQ1[nb][(256 + tid) << 3]);                              \
  } while (0)

__global__ __launch_bounds__(256) void stats_mfma(
    const half_t* __restrict__ Qh, const half_t* __restrict__ Ql,
    const half_t* __restrict__ Kh, const half_t* __restrict__ Kl,
    float* __restrict__ C2) {
  __shared__ half_t sQ0[2][4096], sQ1[2][4096];
  const int tid = threadIdx.x;
  const int w = tid >> 6, lane = tid & 63, c = lane & 15, g = lane >> 4;
  const int lid = blockIdx.y * 16 + blockIdx.x;
  const int bh = (lid & 7) * 8 + ((lid >> 3) & 7);   // XCD-swizzled
  const int xb = lid >> 6;
  const size_t base = (size_t)bh << 18;
  const int kb = xb * 128 + w * 32;
  f32x4 z4 = {0.f, 0.f, 0.f, 0.f};
  f16x8 ka0[2][4], ka1[2][4];
#pragma unroll
  for (int kt = 0; kt < 2; ++kt)
#pragma unroll
    for (int ds = 0; ds < 4; ++ds) {
      size_t a = base + (size_t)(kb + kt * 16 + c) * 128 + ds * 32 + g * 8;
      ka0[kt][ds] = *(const f16x8*)&Kh[a];
      ka1[kt][ds] = *(const f16x8*)&Kl[a];
    }
  float m[2][4], z[2][4];
#pragma unroll
  for (int kt = 0; kt < 2; ++kt)
#pragma unroll
    for (int r = 0; r < 4; ++r) { m[kt][r] = -INFINITY; z[kt][r] = 0.f; }
  STAGE_Q(0, 0);
  __syncthreads();
  for (int t = 0; t < 64; ++t) {
    const int buf = t & 1;
    if (t < 63) STAGE_Q(buf ^ 1, (t + 1) << 5);
#pragma unroll
    for (int qh = 0; qh < 2; ++qh) {
      f16x8 q0v[4], q1v[4];
#pragma unroll
      for (int ds = 0; ds < 4; ++ds) {
        int off = ((qh << 4) | c) * 128 + ((((ds << 2) | g) ^ c) << 3);
        q0v[ds] = *(const f16x8*)&sQ0[buf][off];
        q1v[ds] = *(const f16x8*)&sQ1[buf][off];
      }
#pragma unroll
      for (int kt = 0; kt < 2; ++kt) {
        f32x4 A0 = z4, AX = z4;
#pragma unroll
        for (int ds = 0; ds < 4; ++ds) {
          A0 = MFMA(ka0[kt][ds], q0v[ds], A0, 0, 0, 0);
          AX = MFMA(ka0[kt][ds], q1v[ds], AX, 0, 0, 0);
          AX = MFMA(ka1[kt][ds], q0v[ds], AX, 0, 0, 0);
        }
#pragma unroll
        for (int r = 0; r < 4; ++r) {
          float tt = (A0[r] + AX[r] * RLO) * K1C;
          float mo = m[kt][r];
          float mn = fmaxf(mo, tt);
          float e = __builtin_amdgcn_exp2f(fminf(mo, tt) - mn);
          z[kt][r] = (tt <= mo) ? (z[kt][r] + e) : (z[kt][r] * e + 1.0f);
          m[kt][r] = mn;
        }
      }
    }
    __syncthreads();
  }
#pragma unroll
  for (int mask = 1; mask < 16; mask <<= 1)
#pragma unroll
    for (int kt = 0; kt < 2; ++kt)
#pragma unroll
      for (int r = 0; r < 4; ++r) {
        float mo = __shfl_xor(m[kt][r], mask, 64);
        float zo = __shfl_xor(z[kt][r], mask, 64);
        float mn = fmaxf(m[kt][r], mo);
        z[kt][r] = z[kt][r] * __builtin_amdgcn_exp2f(m[kt][r] - mn) +
                   zo * __builtin_amdgcn_exp2f(mo - mn);
        m[kt][r] = mn;
      }
  if (c == 0) {
#pragma unroll
    for (int kt = 0; kt < 2; ++kt)
#pragma unroll
      for (int r = 0; r < 4; ++r)
        C2[(bh << 11) + kb + kt * 16 + (g << 2) + r] =
            m[kt][r] + __builtin_amdgcn_logf(z[kt][r]);
  }
}

// ---------- attention: 8 waves share dbuf LDS K/V tiles; P=2^(t-C2); O=P@V ----------
// NOTE: K-row chunk swizzle must mask the 5-bit row to 4-bit chunk space (r_ & 15);
// unmasked XOR read past the row (rows 16..31 garbage -> inf -> NaN) in round 3.
#define STAGE_ATTN(nb, ktn) do {                                              \
    int r_ = tid >> 4, chl_ = tid & 15;                                       \
    size_t ro_ = base + (size_t)((ktn) + r_) * 128 + ((chl_ ^ (r_ & 15)) << 3); \
    gld16(&Kh[ro_], &sKh[nb][tid << 3]);                                      \
    gld16(&Kl[ro_], &sKl[nb][tid << 3]);                                      \
    int d_ = tid >> 2, cvl_ = tid & 3;                                        \
    gld16(&Vt[base + (size_t)d_ * 2048 + (ktn) + ((cvl_ ^ ((d_ >> 1) & 3)) << 3)], \
          &sVs[nb][tid << 3]);                                                \
  } while (0)

__global__ __launch_bounds__(512, 4) void attn_mfma(
    const half_t* __restrict__ Qh, const half_t* __restrict__ Ql,
    const half_t* __restrict__ Kh, const half_t* __restrict__ Kl,
    const half_t* __restrict__ Vt, const float* __restrict__ C2,
    float* __restrict__ O) {
  __shared__ half_t sKh[2][4096], sKl[2][4096], sVs[2][4096];
  __shared__ half_t sP[8][16][40];
  __shared__ float sC2[2048];
  const int tid = threadIdx.x;
  const int w = tid >> 6, lane = tid & 63, c = lane & 15, g = lane >> 4;
  const int lid = blockIdx.y * 16 + blockIdx.x;
  const int bh = (lid & 7) * 8 + ((lid >> 3) & 7);   // XCD-swizzled
  const int qx = lid >> 6;
  const size_t base = (size_t)bh << 18;
  const int qb = qx * 128 + w * 16;
  f32x4 z4 = {0.f, 0.f, 0.f, 0.f};
  f16x8 qf0[4], qf1[4];
#pragma unroll
  for (int ds = 0; ds < 4; ++ds) {
    size_t a = base + (size_t)(qb + c) * 128 + ds * 32 + g * 8;
    qf0[ds] = *(const f16x8*)&Qh[a];
    qf1[ds] = *(const f16x8*)&Ql[a];
  }
  f32x4 Oacc[8];
#pragma unroll
  for (int dt = 0; dt < 8; ++dt) Oacc[dt] = z4;
  ((f32x4*)sC2)[tid] = ((const f32x4*)(C2 + ((size_t)bh << 11)))[tid];
  STAGE_ATTN(0, 0);
  __syncthreads();
  for (int t = 0; t < 64; ++t) {
    const int buf = t & 1;
    const int kt = t << 5;
    if (t < 63) STAGE_ATTN(buf ^ 1, kt + 32);
#pragma unroll
    for (int h = 0; h < 2; ++h) {
      f32x4 A0 = z4, AX = z4;
#pragma unroll
      for (int ds = 0; ds < 4; ++ds) {
        int off = ((h << 4) | c) * 128 + ((((ds << 2) | g) ^ c) << 3);
        f16x8 k0v = *(const f16x8*)&sKh[buf][off];
        f16x8 k1v = *(const f16x8*)&sKl[buf][off];
        A0 = MFMA(k0v, qf0[ds], A0, 0, 0, 0);
        AX = MFMA(k0v, qf1[ds], AX, 0, 0, 0);
        AX = MFMA(k1v, qf0[ds], AX, 0, 0, 0);
      }
      f32x4 c2v = *(const f32x4*)&sC2[kt + (h << 4) + (g << 2)];
      f16x4 pv;
#pragma unroll
      for (int r = 0; r < 4; ++r)
        pv[r] = (half_t)__builtin_amdgcn_exp2f((A0[r] + AX[r] * RLO) * K1C - c2v[r]);
      *(f16x4*)&sP[w][c][(h << 4) + (g << 2)] = pv;
    }
    f16x8 pa = *(const f16x8*)&sP[w][c][g << 3];
#pragma unroll
    for (int dt = 0; dt < 8; ++dt) {
      int dd = (dt << 4) + c;
      f16x8 vb = *(const f16x8*)&sVs[buf][dd * 32 + ((g ^ ((dd >> 1) & 3)) << 3)];
      Oacc[dt] = MFMA(pa, vb, Oacc[dt], 0, 0, 0);
    }
    __syncthreads();
  }
#pragma unroll
  for (int dt = 0; dt < 8; ++dt)
#pragma unroll
    for (int r = 0; r < 4; ++r)
      O[base + (size_t)(qb + (g << 2) + r) * 128 + (dt << 4) + c] = Oacc[dt][r];
}

extern "C" void kernel_launch(void* const* d_in, const int* in_sizes, int n_in,
                              void* d_out, int out_size, void* d_ws, size_t ws_size,
                              hipStream_t stream) {
  (void)in_sizes; (void)n_in; (void)out_size; (void)ws_size;
  const float* x = (const float*)d_in[0];
  const float* wq = (const float*)d_in[1];
  const float* wk = (const float*)d_in[2];
  const float* wv = (const float*)d_in[3];
  float* out = (float*)d_out;
  char* ws = (char*)d_ws;
  const size_t S2 = 33554432;  // bytes of one fp16 split [8192][2048]
  half_t* Wth = (half_t*)ws;
  half_t* Wtl = (half_t*)(ws + 8388608);
  half_t* Qh = (half_t*)(ws + 16777216);
  half_t* Ql = (half_t*)(ws + 16777216 + S2);
  half_t* Kh = (half_t*)(ws + 16777216 + 2 * S2);
  half_t* Kl = (half_t*)(ws + 16777216 + 3 * S2);
  half_t* Vh = (half_t*)(ws + 16777216 + 4 * S2);
  half_t* Vth = (half_t*)(ws + 16777216 + 5 * S2);
  float* C2 = (float*)(ws + 16777216 + 6 * S2);
  half_t* Xh = (half_t*)d_out;
  half_t* Xl = (half_t*)((char*)d_out + S2);
  dim3 b(256);
  split_x<<<2048, b, 0, stream>>>(x, Xh, Xl);
  wtrans_split<<<dim3(32, 32), b, 0, stream>>>(wq, Wth, Wtl);
  proj_mfma<<<dim3(16, 64), b, 0, stream>>>(Xh, Xl, Wth, Wtl, Qh, Ql, 0);
  wtrans_split<<<dim3(32, 32), b, 0, stream>>>(wk, Wth, Wtl);
  proj_mfma<<<dim3(16, 64), b, 0, stream>>>(Xh, Xl, Wth, Wtl, Kh, Kl, 0);
  wtrans_split<<<dim3(32, 32), b, 0, stream>>>(wv, Wth, Wtl);
  proj_mfma<<<dim3(16, 64), b, 0, stream>>>(Xh, Xl, Wth, Wtl, Vh, nullptr, 1);
  transpose_v<<<dim3(16, 64), b, 0, stream>>>(Vh, Vth);
  stats_mfma<<<dim3(16, 64), b, 0, stream>>>(Qh, Ql, Kh, Kl, C2);
  attn_mfma<<<dim3(16, 64), dim3(512), 0, stream>>>(Qh, Ql, Kh, Kl, Vth, C2, out);
}

// Round 5
// 1113.999 us; speedup vs baseline: 5.7589x; 1.1500x over previous
//
#include <hip/hip_runtime.h>
#include <math.h>

typedef _Float16 half_t;
typedef __attribute__((ext_vector_type(8))) _Float16 f16x8;
typedef __attribute__((ext_vector_type(4))) _Float16 f16x4;
typedef __attribute__((ext_vector_type(4))) float f32x4;

#define MFMA __builtin_amdgcn_mfma_f32_16x16x32_f16
#define K1C (0.08838834764831845f * 1.4426950408889634f)  // SCALE * log2(e)
#define RLO (1.0f / 2048.0f)

// async global->LDS, 16B per lane (linear dest = base + lane*16)
__device__ inline void gld16(const void* g, void* l) {
  __builtin_amdgcn_global_load_lds(
      (const __attribute__((address_space(1))) uint32_t*)g,
      (__attribute__((address_space(3))) uint32_t*)l, 16, 0, 0);
}

// ---------- split fp32 -> fp16 hi + fp16 lo*2^11 ----------
__global__ __launch_bounds__(256) void split_x(const float* __restrict__ X,
                                               half_t* __restrict__ Xh,
                                               half_t* __restrict__ Xl) {
  size_t i = (size_t)blockIdx.x * 256 + threadIdx.x;
  const size_t stride = (size_t)gridDim.x * 256;
  for (size_t p = i; p < 4194304; p += stride) {
    f32x4 v = ((const f32x4*)X)[p];
    f16x4 h, l;
#pragma unroll
    for (int j = 0; j < 4; ++j) {
      half_t hh = (half_t)v[j];
      h[j] = hh;
      l[j] = (half_t)((v[j] - (float)hh) * 2048.0f);
    }
    ((f16x4*)Xh)[p] = h;
    ((f16x4*)Xl)[p] = l;
  }
}

// ---------- W[2048][2048] -> Wt[n][k] split halves ----------
__global__ __launch_bounds__(256) void wtrans_split(const float* __restrict__ W,
                                                    half_t* __restrict__ Wh,
                                                    half_t* __restrict__ Wl) {
  __shared__ float T[64][68];
  const int tid = threadIdx.x;
  const int k0 = blockIdx.x * 64, n0 = blockIdx.y * 64;
#pragma unroll
  for (int t = 0; t < 4; ++t) {
    int s = t * 256 + tid;
    int kr = s >> 4, nc = (s & 15) * 4;
    f32x4 v = *(const f32x4*)&W[(size_t)(k0 + kr) * 2048 + n0 + nc];
#pragma unroll
    for (int j = 0; j < 4; ++j) T[nc + j][kr] = v[j];
  }
  __syncthreads();
#pragma unroll
  for (int t = 0; t < 4; ++t) {
    int s = t * 256 + tid;
    int nr = s >> 4, kc = (s & 15) * 4;
    f16x4 h, l;
#pragma unroll
    for (int j = 0; j < 4; ++j) {
      float q = T[nr][kc + j];
      half_t hh = (half_t)q;
      h[j] = hh;
      l[j] = (half_t)((q - (float)hh) * 2048.0f);
    }
    *(f16x4*)&Wh[(size_t)(n0 + nr) * 2048 + k0 + kc] = h;
    *(f16x4*)&Wl[(size_t)(n0 + nr) * 2048 + k0 + kc] = l;
  }
}

// ---------- projection GEMM: C[m][n] = sum_k X[m][k]*Wt[n][k], split-fp16 MFMA
// 128x128 tile, BK=32 (32KB LDS -> 2 blocks/CU so barrier drains overlap), XCD-swizzled grid.
// BK=32 swizzle: 64B rows, read chunk g ^ ((c>>1)&3); each consecutive-8-lane group
// hits 8 distinct (row-parity, 16B-slot) bank groups -> conflict-free.
__global__ __launch_bounds__(256, 2) void proj_mfma(
    const half_t* __restrict__ Xh, const half_t* __restrict__ Xl,
    const half_t* __restrict__ Wh, const half_t* __restrict__ Wl,
    half_t* __restrict__ Ch, half_t* __restrict__ Cl, const int mode) {
  __shared__ half_t sAh[4096], sAl[4096], sBh[4096], sBl[4096];
  const int tid = threadIdx.x;
  const int lid = blockIdx.x;
  const int swz = (lid & 7) * 128 + (lid >> 3);  // bijective XCD swizzle (1024%8==0)
  const int m0 = (swz >> 4) << 7, n0 = (swz & 15) << 7;
  const int w = tid >> 6, lane = tid & 63, c = lane & 15, g = lane >> 4;
  const int wr = w >> 1, wc = w & 1;
  f32x4 z4 = {0.f, 0.f, 0.f, 0.f};
  f32x4 acc0[4][4], accX[4][4];
#pragma unroll
  for (int i = 0; i < 4; ++i)
#pragma unroll
    for (int j = 0; j < 4; ++j) { acc0[i][j] = z4; accX[i][j] = z4; }
  for (int k0 = 0; k0 < 2048; k0 += 32) {
#pragma unroll
    for (int t = 0; t < 2; ++t) {
      int s = t * 256 + tid;
      int row = s >> 2;
      int lch = (s & 3) ^ ((row >> 1) & 3);  // pre-swizzled source chunk
      size_t ga = (size_t)(m0 + row) * 2048 + k0 + lch * 8;
      size_t gb = (size_t)(n0 + row) * 2048 + k0 + lch * 8;
      gld16(&Xh[ga], &sAh[s * 8]);
      gld16(&Xl[ga], &sAl[s * 8]);
      gld16(&Wh[gb], &sBh[s * 8]);
      gld16(&Wl[gb], &sBl[s * 8]);
    }
    __syncthreads();
    {
      f16x8 a0[4], a1[4], b0[4], b1[4];
      const int sw = g ^ ((c >> 1) & 3);
#pragma unroll
      for (int i = 0; i < 4; ++i) {
        int ar = wr * 64 + i * 16 + c;
        a0[i] = *(const f16x8*)&sAh[ar * 32 + sw * 8];
        a1[i] = *(const f16x8*)&sAl[ar * 32 + sw * 8];
        int br = wc * 64 + i * 16 + c;
        b0[i] = *(const f16x8*)&sBh[br * 32 + sw * 8];
        b1[i] = *(const f16x8*)&sBl[br * 32 + sw * 8];
      }
#pragma unroll
      for (int i = 0; i < 4; ++i)
#pragma unroll
        for (int j = 0; j < 4; ++j) {
          acc0[i][j] = MFMA(a0[i], b0[j], acc0[i][j], 0, 0, 0);
          if (mode == 0) {
            accX[i][j] = MFMA(a0[i], b1[j], accX[i][j], 0, 0, 0);
            accX[i][j] = MFMA(a1[i], b0[j], accX[i][j], 0, 0, 0);
          }
        }
    }
    __syncthreads();
  }
#pragma unroll
  for (int i = 0; i < 4; ++i)
#pragma unroll
    for (int j = 0; j < 4; ++j) {
      int mbase = m0 + wr * 64 + i * 16 + g * 4;
      int n = n0 + wc * 64 + j * 16 + c;
#pragma unroll
      for (int r = 0; r < 4; ++r) {
        float q = acc0[i][j][r] + accX[i][j][r] * RLO;
        half_t hh = (half_t)q;
        size_t o = (size_t)(mbase + r) * 2048 + n;
        Ch[o] = hh;
        if (mode == 0) Cl[o] = (half_t)((q - (float)hh) * 2048.0f);
      }
    }
}

// ---------- V[bh][k][d] -> Vt[bh][d][k] ----------
__global__ __launch_bounds__(256) void transpose_v(const half_t* __restrict__ V,
                                                   half_t* __restrict__ Vt) {
  __shared__ half_t T[128 * 128];
  const int tid = threadIdx.x;
  const int bh = blockIdx.y, k0 = blockIdx.x * 128;
  const size_t base = (size_t)bh << 18;
#pragma unroll
  for (int t = 0; t < 8; ++t) {
    int s = t * 256 + tid;
    int kr = s >> 4, ch = s & 15;
    int pc = ch ^ ((kr >> 3) & 15);
    *(f16x8*)&T[kr * 128 + pc * 8] =
        *(const f16x8*)&V[base + (size_t)(k0 + kr) * 128 + ch * 8];
  }
  __syncthreads();
#pragma unroll
  for (int t = 0; t < 8; ++t) {
    int s = t * 256 + tid;
    int d = s >> 4, kc = s & 15;
    f16x8 o;
#pragma unroll
    for (int j = 0; j < 8; ++j) {
      int kr = kc * 8 + j;
      int pc = (d >> 3) ^ (kc & 15);
      o[j] = T[kr * 128 + pc * 8 + (d & 7)];
    }
    *(f16x8*)&Vt[base + (size_t)d * 2048 + k0 + kc * 8] = o;
  }
}

// ---------- column-softmax stats: C2[k] = m_k + log2(z_k) ----------
// 4 waves x 32 k each; Q (hi+lo) staged in LDS double-buffered, shared.
#define STAGE_Q(nb, qn) do {                                                  \
    int r0_ = tid >> 4, cl0_ = tid & 15;                                      \
    size_t o0_ = base + (size_t)((qn) + r0_) * 128 + ((cl0_ ^ r0_) << 3);     \
    gld16(&Qh[o0_], &sQ0[nb][tid << 3]);                                      \
    gld16(&Ql[o0_], &sQ1[nb][tid << 3]);                                      \
    int r1_ = 16 + r0_;                                                       \
    size_t o1_ = base + (size_t)((qn) + r1_) * 128 + ((cl0_ ^ (r1_ & 15)) << 3); \
    gld16(&Qh[o1_], &sQ0[nb][(256 + tid) << 3]);                              \
    gld16(&Ql[o1_], &sQ1[nb][(256 + tid) << 3]);                              \
  } while (0)

__global__ __launch_bounds__(256) void stats_mfma(
    const half_t* __restrict__ Qh, const half_t* __restrict__ Ql,
    const half_t* __restrict__ Kh, const half_t* __restrict__ Kl,
    float* __restrict__ C2) {
  __shared__ half_t sQ0[2][4096], sQ1[2][4096];
  const int tid = threadIdx.x;
  const int w = tid >> 6, lane = tid & 63, c = lane & 15, g = lane >> 4;
  const int lid = blockIdx.y * 16 + blockIdx.x;
  const int bh = (lid & 7) * 8 + ((lid >> 3) & 7);   // XCD-swizzled
  const int xb = lid >> 6;
  const size_t base = (size_t)bh << 18;
  const int kb = xb * 128 + w * 32;
  f32x4 z4 = {0.f, 0.f, 0.f, 0.f};
  f16x8 ka0[2][4], ka1[2][4];
#pragma unroll
  for (int kt = 0; kt < 2; ++kt)
#pragma unroll
    for (int ds = 0; ds < 4; ++ds) {
      size_t a = base + (size_t)(kb + kt * 16 + c) * 128 + ds * 32 + g * 8;
      ka0[kt][ds] = *(const f16x8*)&Kh[a];
      ka1[kt][ds] = *(const f16x8*)&Kl[a];
    }
  float m[2][4], z[2][4];
#pragma unroll
  for (int kt = 0; kt < 2; ++kt)
#pragma unroll
    for (int r = 0; r < 4; ++r) { m[kt][r] = -INFINITY; z[kt][r] = 0.f; }
  STAGE_Q(0, 0);
  __syncthreads();
  for (int t = 0; t < 64; ++t) {
    const int buf = t & 1;
    if (t < 63) STAGE_Q(buf ^ 1, (t + 1) << 5);
#pragma unroll
    for (int qh = 0; qh < 2; ++qh) {
      f16x8 q0v[4], q1v[4];
#pragma unroll
      for (int ds = 0; ds < 4; ++ds) {
        int off = ((qh << 4) | c) * 128 + ((((ds << 2) | g) ^ c) << 3);
        q0v[ds] = *(const f16x8*)&sQ0[buf][off];
        q1v[ds] = *(const f16x8*)&sQ1[buf][off];
      }
#pragma unroll
      for (int kt = 0; kt < 2; ++kt) {
        f32x4 A0 = z4, AX = z4;
#pragma unroll
        for (int ds = 0; ds < 4; ++ds) {
          A0 = MFMA(ka0[kt][ds], q0v[ds], A0, 0, 0, 0);
          AX = MFMA(ka0[kt][ds], q1v[ds], AX, 0, 0, 0);
          AX = MFMA(ka1[kt][ds], q0v[ds], AX, 0, 0, 0);
        }
#pragma unroll
        for (int r = 0; r < 4; ++r) {
          float tt = (A0[r] + AX[r] * RLO) * K1C;
          float mo = m[kt][r];
          float mn = fmaxf(mo, tt);
          float e = __builtin_amdgcn_exp2f(fminf(mo, tt) - mn);
          z[kt][r] = (tt <= mo) ? (z[kt][r] + e) : (z[kt][r] * e + 1.0f);
          m[kt][r] = mn;
        }
      }
    }
    __syncthreads();
  }
#pragma unroll
  for (int mask = 1; mask < 16; mask <<= 1)
#pragma unroll
    for (int kt = 0; kt < 2; ++kt)
#pragma unroll
      for (int r = 0; r < 4; ++r) {
        float mo = __shfl_xor(m[kt][r], mask, 64);
        float zo = __shfl_xor(z[kt][r], mask, 64);
        float mn = fmaxf(m[kt][r], mo);
        z[kt][r] = z[kt][r] * __builtin_amdgcn_exp2f(m[kt][r] - mn) +
                   zo * __builtin_amdgcn_exp2f(mo - mn);
        m[kt][r] = mn;
      }
  if (c == 0) {
#pragma unroll
    for (int kt = 0; kt < 2; ++kt)
#pragma unroll
      for (int r = 0; r < 4; ++r)
        C2[(bh << 11) + kb + kt * 16 + (g << 2) + r] =
            m[kt][r] + __builtin_amdgcn_logf(z[kt][r]);
  }
}

// ---------- attention: 8 waves share dbuf LDS K/V tiles; P=2^(t-C2); O=P@V ----------
#define STAGE_ATTN(nb, ktn) do {                                              \
    int r_ = tid >> 4, chl_ = tid & 15;                                       \
    size_t ro_ = base + (size_t)((ktn) + r_) * 128 + ((chl_ ^ (r_ & 15)) << 3); \
    gld16(&Kh[ro_], &sKh[nb][tid << 3]);                                      \
    gld16(&Kl[ro_], &sKl[nb][tid << 3]);                                      \
    int d_ = tid >> 2, cvl_ = tid & 3;                                        \
    gld16(&Vt[base + (size_t)d_ * 2048 + (ktn) + ((cvl_ ^ ((d_ >> 1) & 3)) << 3)], \
          &sVs[nb][tid << 3]);                                                \
  } while (0)

__global__ __launch_bounds__(512, 4) void attn_mfma(
    const half_t* __restrict__ Qh, const half_t* __restrict__ Ql,
    const half_t* __restrict__ Kh, const half_t* __restrict__ Kl,
    const half_t* __restrict__ Vt, const float* __restrict__ C2,
    float* __restrict__ O) {
  __shared__ half_t sKh[2][4096], sKl[2][4096], sVs[2][4096];
  __shared__ half_t sP[8][16][40];
  __shared__ float sC2[2048];
  const int tid = threadIdx.x;
  const int w = tid >> 6, lane = tid & 63, c = lane & 15, g = lane >> 4;
  const int lid = blockIdx.y * 16 + blockIdx.x;
  const int bh = (lid & 7) * 8 + ((lid >> 3) & 7);   // XCD-swizzled
  const int qx = lid >> 6;
  const size_t base = (size_t)bh << 18;
  const int qb = qx * 128 + w * 16;
  f32x4 z4 = {0.f, 0.f, 0.f, 0.f};
  f16x8 qf0[4], qf1[4];
#pragma unroll
  for (int ds = 0; ds < 4; ++ds) {
    size_t a = base + (size_t)(qb + c) * 128 + ds * 32 + g * 8;
    qf0[ds] = *(const f16x8*)&Qh[a];
    qf1[ds] = *(const f16x8*)&Ql[a];
  }
  f32x4 Oacc[8];
#pragma unroll
  for (int dt = 0; dt < 8; ++dt) Oacc[dt] = z4;
  ((f32x4*)sC2)[tid] = ((const f32x4*)(C2 + ((size_t)bh << 11)))[tid];
  STAGE_ATTN(0, 0);
  __syncthreads();
  for (int t = 0; t < 64; ++t) {
    const int buf = t & 1;
    const int kt = t << 5;
    if (t < 63) STAGE_ATTN(buf ^ 1, kt + 32);
#pragma unroll
    for (int h = 0; h < 2; ++h) {
      f32x4 A0 = z4, AX = z4;
#pragma unroll
      for (int ds = 0; ds < 4; ++ds) {
        int off = ((h << 4) | c) * 128 + ((((ds << 2) | g) ^ c) << 3);
        f16x8 k0v = *(const f16x8*)&sKh[buf][off];
        f16x8 k1v = *(const f16x8*)&sKl[buf][off];
        A0 = MFMA(k0v, qf0[ds], A0, 0, 0, 0);
        AX = MFMA(k0v, qf1[ds], AX, 0, 0, 0);
        AX = MFMA(k1v, qf0[ds], AX, 0, 0, 0);
      }
      f32x4 c2v = *(const f32x4*)&sC2[kt + (h << 4) + (g << 2)];
      f16x4 pv;
#pragma unroll
      for (int r = 0; r < 4; ++r)
        pv[r] = (half_t)__builtin_amdgcn_exp2f((A0[r] + AX[r] * RLO) * K1C - c2v[r]);
      *(f16x4*)&sP[w][c][(h << 4) + (g << 2)] = pv;
    }
    f16x8 pa = *(const f16x8*)&sP[w][c][g << 3];
#pragma unroll
    for (int dt = 0; dt < 8; ++dt) {
      int dd = (dt << 4) + c;
      f16x8 vb = *(const f16x8*)&sVs[buf][dd * 32 + ((g ^ ((dd >> 1) & 3)) << 3)];
      Oacc[dt] = MFMA(pa, vb, Oacc[dt], 0, 0, 0);
    }
    __syncthreads();
  }
#pragma unroll
  for (int dt = 0; dt < 8; ++dt)
#pragma unroll
    for (int r = 0; r < 4; ++r)
      O[base + (size_t)(qb + (g << 2) + r) * 128 + (dt << 4) + c] = Oacc[dt][r];
}

extern "C" void kernel_launch(void* const* d_in, const int* in_sizes, int n_in,
                              void* d_out, int out_size, void* d_ws, size_t ws_size,
                              hipStream_t stream) {
  (void)in_sizes; (void)n_in; (void)out_size; (void)ws_size;
  const float* x = (const float*)d_in[0];
  const float* wq = (const float*)d_in[1];
  const float* wk = (const float*)d_in[2];
  const float* wv = (const float*)d_in[3];
  float* out = (float*)d_out;
  char* ws = (char*)d_ws;
  const size_t S2 = 33554432;  // bytes of one fp16 split [8192][2048]
  half_t* Wth = (half_t*)ws;
  half_t* Wtl = (half_t*)(ws + 8388608);
  half_t* Qh = (half_t*)(ws + 16777216);
  half_t* Ql = (half_t*)(ws + 16777216 + S2);
  half_t* Kh = (half_t*)(ws + 16777216 + 2 * S2);
  half_t* Kl = (half_t*)(ws + 16777216 + 3 * S2);
  half_t* Vh = (half_t*)(ws + 16777216 + 4 * S2);
  half_t* Vth = (half_t*)(ws + 16777216 + 5 * S2);
  float* C2 = (float*)(ws + 16777216 + 6 * S2);
  half_t* Xh = (half_t*)d_out;
  half_t* Xl = (half_t*)((char*)d_out + S2);
  dim3 b(256);
  split_x<<<2048, b, 0, stream>>>(x, Xh, Xl);
  wtrans_split<<<dim3(32, 32), b, 0, stream>>>(wq, Wth, Wtl);
  proj_mfma<<<dim3(1024), b, 0, stream>>>(Xh, Xl, Wth, Wtl, Qh, Ql, 0);
  wtrans_split<<<dim3(32, 32), b, 0, stream>>>(wk, Wth, Wtl);
  proj_mfma<<<dim3(1024), b, 0, stream>>>(Xh, Xl, Wth, Wtl, Kh, Kl, 0);
  wtrans_split<<<dim3(32, 32), b, 0, stream>>>(wv, Wth, Wtl);
  proj_mfma<<<dim3(1024), b, 0, stream>>>(Xh, Xl, Wth, Wtl, Vh, nullptr, 1);
  transpose_v<<<dim3(16, 64), b, 0, stream>>>(Vh, Vth);
  stats_mfma<<<dim3(16, 64), b, 0, stream>>>(Qh, Ql, Kh, Kl, C2);
  attn_mfma<<<dim3(16, 64), dim3(512), 0, stream>>>(Qh, Ql, Kh, Kl, Vth, C2, out);
}

// Round 6
// 1085.037 us; speedup vs baseline: 5.9126x; 1.0267x over previous
//
#include <hip/hip_runtime.h>
#include <math.h>

typedef _Float16 half_t;
typedef __attribute__((ext_vector_type(8))) _Float16 f16x8;
typedef __attribute__((ext_vector_type(4))) _Float16 f16x4;
typedef __attribute__((ext_vector_type(4))) float f32x4;

#define MFMA __builtin_amdgcn_mfma_f32_16x16x32_f16
#define K1C (0.08838834764831845f * 1.4426950408889634f)  // SCALE * log2(e)
#define RLO (1.0f / 2048.0f)

// async global->LDS, 16B per lane (linear dest = base + lane*16)
__device__ inline void gld16(const void* g, void* l) {
  __builtin_amdgcn_global_load_lds(
      (const __attribute__((address_space(1))) uint32_t*)g,
      (__attribute__((address_space(3))) uint32_t*)l, 16, 0, 0);
}

// ---------- split fp32 -> fp16 hi + fp16 lo*2^11 ----------
__global__ __launch_bounds__(256) void split_x(const float* __restrict__ X,
                                               half_t* __restrict__ Xh,
                                               half_t* __restrict__ Xl) {
  size_t i = (size_t)blockIdx.x * 256 + threadIdx.x;
  const size_t stride = (size_t)gridDim.x * 256;
  for (size_t p = i; p < 4194304; p += stride) {
    f32x4 v = ((const f32x4*)X)[p];
    f16x4 h, l;
#pragma unroll
    for (int j = 0; j < 4; ++j) {
      half_t hh = (half_t)v[j];
      h[j] = hh;
      l[j] = (half_t)((v[j] - (float)hh) * 2048.0f);
    }
    ((f16x4*)Xh)[p] = h;
    ((f16x4*)Xl)[p] = l;
  }
}

// ---------- W[2048][2048] -> Wt[n][k] split halves ----------
__global__ __launch_bounds__(256) void wtrans_split(const float* __restrict__ W,
                                                    half_t* __restrict__ Wh,
                                                    half_t* __restrict__ Wl) {
  __shared__ float T[64][68];
  const int tid = threadIdx.x;
  const int k0 = blockIdx.x * 64, n0 = blockIdx.y * 64;
#pragma unroll
  for (int t = 0; t < 4; ++t) {
    int s = t * 256 + tid;
    int kr = s >> 4, nc = (s & 15) * 4;
    f32x4 v = *(const f32x4*)&W[(size_t)(k0 + kr) * 2048 + n0 + nc];
#pragma unroll
    for (int j = 0; j < 4; ++j) T[nc + j][kr] = v[j];
  }
  __syncthreads();
#pragma unroll
  for (int t = 0; t < 4; ++t) {
    int s = t * 256 + tid;
    int nr = s >> 4, kc = (s & 15) * 4;
    f16x4 h, l;
#pragma unroll
    for (int j = 0; j < 4; ++j) {
      float q = T[nr][kc + j];
      half_t hh = (half_t)q;
      h[j] = hh;
      l[j] = (half_t)((q - (float)hh) * 2048.0f);
    }
    *(f16x4*)&Wh[(size_t)(n0 + nr) * 2048 + k0 + kc] = h;
    *(f16x4*)&Wl[(size_t)(n0 + nr) * 2048 + k0 + kc] = l;
  }
}

// ---------- projection GEMM: C[m][n] = sum_k X[m][k]*Wt[n][k], split-fp16 MFMA
// 128x128 tile, BK=32, DOUBLE-BUFFERED LDS (64KB): stage(buf^1) -> compute(buf) ->
// one barrier per K-step (loads fly during MFMA phase; vmcnt drained at barrier).
#define STAGE_P(nb, kn) do {                                                  \
    _Pragma("unroll")                                                         \
    for (int t_ = 0; t_ < 2; ++t_) {                                          \
      int s_ = t_ * 256 + tid;                                                \
      int row_ = s_ >> 2;                                                     \
      int lch_ = (s_ & 3) ^ ((row_ >> 1) & 3);  /* pre-swizzled source */     \
      size_t ga_ = (size_t)(m0 + row_) * 2048 + (kn) + lch_ * 8;              \
      size_t gb_ = (size_t)(n0 + row_) * 2048 + (kn) + lch_ * 8;              \
      gld16(&Xh[ga_], &sAh[nb][s_ * 8]);                                      \
      gld16(&Xl[ga_], &sAl[nb][s_ * 8]);                                      \
      gld16(&Wh[gb_], &sBh[nb][s_ * 8]);                                      \
      gld16(&Wl[gb_], &sBl[nb][s_ * 8]);                                      \
    }                                                                         \
  } while (0)

__global__ __launch_bounds__(256, 2) void proj_mfma(
    const half_t* __restrict__ Xh, const half_t* __restrict__ Xl,
    const half_t* __restrict__ Wh, const half_t* __restrict__ Wl,
    half_t* __restrict__ Ch, half_t* __restrict__ Cl, const int mode) {
  __shared__ half_t sAh[2][4096], sAl[2][4096], sBh[2][4096], sBl[2][4096];
  const int tid = threadIdx.x;
  const int lid = blockIdx.x;
  const int swz = (lid & 7) * 128 + (lid >> 3);  // bijective XCD swizzle (1024%8==0)
  const int m0 = (swz >> 4) << 7, n0 = (swz & 15) << 7;
  const int w = tid >> 6, lane = tid & 63, c = lane & 15, g = lane >> 4;
  const int wr = w >> 1, wc = w & 1;
  f32x4 z4 = {0.f, 0.f, 0.f, 0.f};
  f32x4 acc0[4][4], accX[4][4];
#pragma unroll
  for (int i = 0; i < 4; ++i)
#pragma unroll
    for (int j = 0; j < 4; ++j) { acc0[i][j] = z4; accX[i][j] = z4; }
  STAGE_P(0, 0);
  __syncthreads();
  for (int k0 = 0; k0 < 2048; k0 += 32) {
    const int buf = (k0 >> 5) & 1;
    if (k0 < 2016) STAGE_P(buf ^ 1, k0 + 32);
    {
      f16x8 a0[4], a1[4], b0[4], b1[4];
      const int sw = g ^ ((c >> 1) & 3);
#pragma unroll
      for (int i = 0; i < 4; ++i) {
        int ar = wr * 64 + i * 16 + c;
        a0[i] = *(const f16x8*)&sAh[buf][ar * 32 + sw * 8];
        a1[i] = *(const f16x8*)&sAl[buf][ar * 32 + sw * 8];
        int br = wc * 64 + i * 16 + c;
        b0[i] = *(const f16x8*)&sBh[buf][br * 32 + sw * 8];
        b1[i] = *(const f16x8*)&sBl[buf][br * 32 + sw * 8];
      }
#pragma unroll
      for (int i = 0; i < 4; ++i)
#pragma unroll
        for (int j = 0; j < 4; ++j) {
          acc0[i][j] = MFMA(a0[i], b0[j], acc0[i][j], 0, 0, 0);
          if (mode == 0) {
            accX[i][j] = MFMA(a0[i], b1[j], accX[i][j], 0, 0, 0);
            accX[i][j] = MFMA(a1[i], b0[j], accX[i][j], 0, 0, 0);
          }
        }
    }
    __syncthreads();
  }
#pragma unroll
  for (int i = 0; i < 4; ++i)
#pragma unroll
    for (int j = 0; j < 4; ++j) {
      int mbase = m0 + wr * 64 + i * 16 + g * 4;
      int n = n0 + wc * 64 + j * 16 + c;
#pragma unroll
      for (int r = 0; r < 4; ++r) {
        float q = acc0[i][j][r] + accX[i][j][r] * RLO;
        half_t hh = (half_t)q;
        size_t o = (size_t)(mbase + r) * 2048 + n;
        Ch[o] = hh;
        if (mode == 0) Cl[o] = (half_t)((q - (float)hh) * 2048.0f);
      }
    }
}

// ---------- V[bh][k][d] -> Vt[bh][d][k] ----------
__global__ __launch_bounds__(256) void transpose_v(const half_t* __restrict__ V,
                                                   half_t* __restrict__ Vt) {
  __shared__ half_t T[128 * 128];
  const int tid = threadIdx.x;
  const int bh = blockIdx.y, k0 = blockIdx.x * 128;
  const size_t base = (size_t)bh << 18;
#pragma unroll
  for (int t = 0; t < 8; ++t) {
    int s = t * 256 + tid;
    int kr = s >> 4, ch = s & 15;
    int pc = ch ^ ((kr >> 3) & 15);
    *(f16x8*)&T[kr * 128 + pc * 8] =
        *(const f16x8*)&V[base + (size_t)(k0 + kr) * 128 + ch * 8];
  }
  __syncthreads();
#pragma unroll
  for (int t = 0; t < 8; ++t) {
    int s = t * 256 + tid;
    int d = s >> 4, kc = s & 15;
    f16x8 o;
#pragma unroll
    for (int j = 0; j < 8; ++j) {
      int kr = kc * 8 + j;
      int pc = (d >> 3) ^ (kc & 15);
      o[j] = T[kr * 128 + pc * 8 + (d & 7)];
    }
    *(f16x8*)&Vt[base + (size_t)d * 2048 + k0 + kc * 8] = o;
  }
}

// ---------- column-softmax stats: C2[k] = m_k + log2(z_k) ----------
// 4 waves x 64 k each (K frags register-persistent); Q staged in dbuf LDS, shared.
// Per-CU: MFMA/VALU unchanged vs 32k/wave, but ds_read/staging/barriers halved.
#define STAGE_Q(nb, qn) do {                                                  \
    int r0_ = tid >> 4, cl0_ = tid & 15;                                      \
    size_t o0_ = base + (size_t)((qn) + r0_) * 128 + ((cl0_ ^ r0_) << 3);     \
    gld16(&Qh[o0_], &sQ0[nb][tid << 3]);                                      \
    gld16(&Ql[o0_], &sQ1[nb][tid << 3]);                                      \
    int r1_ = 16 + r0_;                                                       \
    size_t o1_ = base + (size_t)((qn) + r1_) * 128 + ((cl0_ ^ (r1_ & 15)) << 3); \
    gld16(&Qh[o1_], &sQ0[nb][(256 + tid) << 3]);                              \
    gld16(&Ql[o1_], &sQ1[nb][(256 + tid) << 3]);                              \
  } while (0)

__global__ __launch_bounds__(256, 2) void stats_mfma(
    const half_t* __restrict__ Qh, const half_t* __restrict__ Ql,
    const half_t* __restrict__ Kh, const half_t* __restrict__ Kl,
    float* __restrict__ C2) {
  __shared__ half_t sQ0[2][4096], sQ1[2][4096];
  const int tid = threadIdx.x;
  const int w = tid >> 6, lane = tid & 63, c = lane & 15, g = lane >> 4;
  const int lid = blockIdx.y * 8 + blockIdx.x;
  const int bh = (lid & 7) * 8 + ((lid >> 3) & 7);   // XCD-swizzled
  const int xb = lid >> 6;
  const size_t base = (size_t)bh << 18;
  const int kb = xb * 256 + w * 64;
  f32x4 z4 = {0.f, 0.f, 0.f, 0.f};
  f16x8 ka0[4][4], ka1[4][4];
#pragma unroll
  for (int kt = 0; kt < 4; ++kt)
#pragma unroll
    for (int ds = 0; ds < 4; ++ds) {
      size_t a = base + (size_t)(kb + kt * 16 + c) * 128 + ds * 32 + g * 8;
      ka0[kt][ds] = *(const f16x8*)&Kh[a];
      ka1[kt][ds] = *(const f16x8*)&Kl[a];
    }
  float m[4][4], z[4][4];
#pragma unroll
  for (int kt = 0; kt < 4; ++kt)
#pragma unroll
    for (int r = 0; r < 4; ++r) { m[kt][r] = -INFINITY; z[kt][r] = 0.f; }
  STAGE_Q(0, 0);
  __syncthreads();
  for (int t = 0; t < 64; ++t) {
    const int buf = t & 1;
    if (t < 63) STAGE_Q(buf ^ 1, (t + 1) << 5);
#pragma unroll
    for (int qh = 0; qh < 2; ++qh) {
      f16x8 q0v[4], q1v[4];
#pragma unroll
      for (int ds = 0; ds < 4; ++ds) {
        int off = ((qh << 4) | c) * 128 + ((((ds << 2) | g) ^ c) << 3);
        q0v[ds] = *(const f16x8*)&sQ0[buf][off];
        q1v[ds] = *(const f16x8*)&sQ1[buf][off];
      }
#pragma unroll
      for (int kt = 0; kt < 4; ++kt) {
        f32x4 A0 = z4, AX = z4;
#pragma unroll
        for (int ds = 0; ds < 4; ++ds) {
          A0 = MFMA(ka0[kt][ds], q0v[ds], A0, 0, 0, 0);
          AX = MFMA(ka0[kt][ds], q1v[ds], AX, 0, 0, 0);
          AX = MFMA(ka1[kt][ds], q0v[ds], AX, 0, 0, 0);
        }
#pragma unroll
        for (int r = 0; r < 4; ++r) {
          float tt = (A0[r] + AX[r] * RLO) * K1C;
          float mo = m[kt][r];
          float mn = fmaxf(mo, tt);
          float e = __builtin_amdgcn_exp2f(fminf(mo, tt) - mn);
          z[kt][r] = (tt <= mo) ? (z[kt][r] + e) : (z[kt][r] * e + 1.0f);
          m[kt][r] = mn;
        }
      }
    }
    __syncthreads();
  }
#pragma unroll
  for (int mask = 1; mask < 16; mask <<= 1)
#pragma unroll
    for (int kt = 0; kt < 4; ++kt)
#pragma unroll
      for (int r = 0; r < 4; ++r) {
        float mo = __shfl_xor(m[kt][r], mask, 64);
        float zo = __shfl_xor(z[kt][r], mask, 64);
        float mn = fmaxf(m[kt][r], mo);
        z[kt][r] = z[kt][r] * __builtin_amdgcn_exp2f(m[kt][r] - mn) +
                   zo * __builtin_amdgcn_exp2f(mo - mn);
        m[kt][r] = mn;
      }
  if (c == 0) {
#pragma unroll
    for (int kt = 0; kt < 4; ++kt)
#pragma unroll
      for (int r = 0; r < 4; ++r)
        C2[(bh << 11) + kb + kt * 16 + (g << 2) + r] =
            m[kt][r] + __builtin_amdgcn_logf(z[kt][r]);
  }
}

// ---------- attention: 8 waves share dbuf LDS K/V tiles; P=2^(t-C2); O=P@V ----------
#define STAGE_ATTN(nb, ktn) do {                                              \
    int r_ = tid >> 4, chl_ = tid & 15;                                       \
    size_t ro_ = base + (size_t)((ktn) + r_) * 128 + ((chl_ ^ (r_ & 15)) << 3); \
    gld16(&Kh[ro_], &sKh[nb][tid << 3]);                                      \
    gld16(&Kl[ro_], &sKl[nb][tid << 3]);                                      \
    int d_ = tid >> 2, cvl_ = tid & 3;                                        \
    gld16(&Vt[base + (size_t)d_ * 2048 + (ktn) + ((cvl_ ^ ((d_ >> 1) & 3)) << 3)], \
          &sVs[nb][tid << 3]);                                                \
  } while (0)

__global__ __launch_bounds__(512, 4) void attn_mfma(
    const half_t* __restrict__ Qh, const half_t* __restrict__ Ql,
    const half_t* __restrict__ Kh, const half_t* __restrict__ Kl,
    const half_t* __restrict__ Vt, const float* __restrict__ C2,
    float* __restrict__ O) {
  __shared__ half_t sKh[2][4096], sKl[2][4096], sVs[2][4096];
  __shared__ half_t sP[8][16][40];
  __shared__ float sC2[2048];
  const int tid = threadIdx.x;
  const int w = tid >> 6, lane = tid & 63, c = lane & 15, g = lane >> 4;
  const int lid = blockIdx.y * 16 + blockIdx.x;
  const int bh = (lid & 7) * 8 + ((lid >> 3) & 7);   // XCD-swizzled
  const int qx = lid >> 6;
  const size_t base = (size_t)bh << 18;
  const int qb = qx * 128 + w * 16;
  f32x4 z4 = {0.f, 0.f, 0.f, 0.f};
  f16x8 qf0[4], qf1[4];
#pragma unroll
  for (int ds = 0; ds < 4; ++ds) {
    size_t a = base + (size_t)(qb + c) * 128 + ds * 32 + g * 8;
    qf0[ds] = *(const f16x8*)&Qh[a];
    qf1[ds] = *(const f16x8*)&Ql[a];
  }
  f32x4 Oacc[8];
#pragma unroll
  for (int dt = 0; dt < 8; ++dt) Oacc[dt] = z4;
  ((f32x4*)sC2)[tid] = ((const f32x4*)(C2 + ((size_t)bh << 11)))[tid];
  STAGE_ATTN(0, 0);
  __syncthreads();
  for (int t = 0; t < 64; ++t) {
    const int buf = t & 1;
    const int kt = t << 5;
    if (t < 63) STAGE_ATTN(buf ^ 1, kt + 32);
#pragma unroll
    for (int h = 0; h < 2; ++h) {
      f32x4 A0 = z4, AX = z4;
#pragma unroll
      for (int ds = 0; ds < 4; ++ds) {
        int off = ((h << 4) | c) * 128 + ((((ds << 2) | g) ^ c) << 3);
        f16x8 k0v = *(const f16x8*)&sKh[buf][off];
        f16x8 k1v = *(const f16x8*)&sKl[buf][off];
        A0 = MFMA(k0v, qf0[ds], A0, 0, 0, 0);
        AX = MFMA(k0v, qf1[ds], AX, 0, 0, 0);
        AX = MFMA(k1v, qf0[ds], AX, 0, 0, 0);
      }
      f32x4 c2v = *(const f32x4*)&sC2[kt + (h << 4) + (g << 2)];
      f16x4 pv;
#pragma unroll
      for (int r = 0; r < 4; ++r)
        pv[r] = (half_t)__builtin_amdgcn_exp2f((A0[r] + AX[r] * RLO) * K1C - c2v[r]);
      *(f16x4*)&sP[w][c][(h << 4) + (g << 2)] = pv;
    }
    f16x8 pa = *(const f16x8*)&sP[w][c][g << 3];
#pragma unroll
    for (int dt = 0; dt < 8; ++dt) {
      int dd = (dt << 4) + c;
      f16x8 vb = *(const f16x8*)&sVs[buf][dd * 32 + ((g ^ ((dd >> 1) & 3)) << 3)];
      Oacc[dt] = MFMA(pa, vb, Oacc[dt], 0, 0, 0);
    }
    __syncthreads();
  }
#pragma unroll
  for (int dt = 0; dt < 8; ++dt)
#pragma unroll
    for (int r = 0; r < 4; ++r)
      O[base + (size_t)(qb + (g << 2) + r) * 128 + (dt << 4) + c] = Oacc[dt][r];
}

extern "C" void kernel_launch(void* const* d_in, const int* in_sizes, int n_in,
                              void* d_out, int out_size, void* d_ws, size_t ws_size,
                              hipStream_t stream) {
  (void)in_sizes; (void)n_in; (void)out_size; (void)ws_size;
  const float* x = (const float*)d_in[0];
  const float* wq = (const float*)d_in[1];
  const float* wk = (const float*)d_in[2];
  const float* wv = (const float*)d_in[3];
  float* out = (float*)d_out;
  char* ws = (char*)d_ws;
  const size_t S2 = 33554432;  // bytes of one fp16 split [8192][2048]
  half_t* Wth = (half_t*)ws;
  half_t* Wtl = (half_t*)(ws + 8388608);
  half_t* Qh = (half_t*)(ws + 16777216);
  half_t* Ql = (half_t*)(ws + 16777216 + S2);
  half_t* Kh = (half_t*)(ws + 16777216 + 2 * S2);
  half_t* Kl = (half_t*)(ws + 16777216 + 3 * S2);
  half_t* Vh = (half_t*)(ws + 16777216 + 4 * S2);
  half_t* Vth = (half_t*)(ws + 16777216 + 5 * S2);
  float* C2 = (float*)(ws + 16777216 + 6 * S2);
  half_t* Xh = (half_t*)d_out;
  half_t* Xl = (half_t*)((char*)d_out + S2);
  dim3 b(256);
  split_x<<<2048, b, 0, stream>>>(x, Xh, Xl);
  wtrans_split<<<dim3(32, 32), b, 0, stream>>>(wq, Wth, Wtl);
  proj_mfma<<<dim3(1024), b, 0, stream>>>(Xh, Xl, Wth, Wtl, Qh, Ql, 0);
  wtrans_split<<<dim3(32, 32), b, 0, stream>>>(wk, Wth, Wtl);
  proj_mfma<<<dim3(1024), b, 0, stream>>>(Xh, Xl, Wth, Wtl, Kh, Kl, 0);
  wtrans_split<<<dim3(32, 32), b, 0, stream>>>(wv, Wth, Wtl);
  proj_mfma<<<dim3(1024), b, 0, stream>>>(Xh, Xl, Wth, Wtl, Vh, nullptr, 1);
  transpose_v<<<dim3(16, 64), b, 0, stream>>>(Vh, Vth);
  stats_mfma<<<dim3(8, 64), b, 0, stream>>>(Qh, Ql, Kh, Kl, C2);
  attn_mfma<<<dim3(16, 64), dim3(512), 0, stream>>>(Qh, Ql, Kh, Kl, Vth, C2, out);
}

// Round 7
// 1075.991 us; speedup vs baseline: 5.9623x; 1.0084x over previous
//
#include <hip/hip_runtime.h>
#include <math.h>

typedef _Float16 half_t;
typedef __attribute__((ext_vector_type(8))) _Float16 f16x8;
typedef __attribute__((ext_vector_type(4))) _Float16 f16x4;
typedef __attribute__((ext_vector_type(4))) float f32x4;
typedef __attribute__((ext_vector_type(16))) float f32x16;

#define MFMA __builtin_amdgcn_mfma_f32_16x16x32_f16
#define MFMA32 __builtin_amdgcn_mfma_f32_32x32x16_f16
#define K1C (0.08838834764831845f * 1.4426950408889634f)  // SCALE * log2(e)
#define RLO (1.0f / 2048.0f)

// async global->LDS, 16B per lane (linear dest = base + lane*16)
__device__ inline void gld16(const void* g, void* l) {
  __builtin_amdgcn_global_load_lds(
      (const __attribute__((address_space(1))) uint32_t*)g,
      (__attribute__((address_space(3))) uint32_t*)l, 16, 0, 0);
}

// ---------- split fp32 -> fp16 hi + fp16 lo*2^11 ----------
__global__ __launch_bounds__(256) void split_x(const float* __restrict__ X,
                                               half_t* __restrict__ Xh,
                                               half_t* __restrict__ Xl) {
  size_t i = (size_t)blockIdx.x * 256 + threadIdx.x;
  const size_t stride = (size_t)gridDim.x * 256;
  for (size_t p = i; p < 4194304; p += stride) {
    f32x4 v = ((const f32x4*)X)[p];
    f16x4 h, l;
#pragma unroll
    for (int j = 0; j < 4; ++j) {
      half_t hh = (half_t)v[j];
      h[j] = hh;
      l[j] = (half_t)((v[j] - (float)hh) * 2048.0f);
    }
    ((f16x4*)Xh)[p] = h;
    ((f16x4*)Xl)[p] = l;
  }
}

// ---------- W[2048][2048] -> Wt[n][k] split halves ----------
__global__ __launch_bounds__(256) void wtrans_split(const float* __restrict__ W,
                                                    half_t* __restrict__ Wh,
                                                    half_t* __restrict__ Wl) {
  __shared__ float T[64][68];
  const int tid = threadIdx.x;
  const int k0 = blockIdx.x * 64, n0 = blockIdx.y * 64;
#pragma unroll
  for (int t = 0; t < 4; ++t) {
    int s = t * 256 + tid;
    int kr = s >> 4, nc = (s & 15) * 4;
    f32x4 v = *(const f32x4*)&W[(size_t)(k0 + kr) * 2048 + n0 + nc];
#pragma unroll
    for (int j = 0; j < 4; ++j) T[nc + j][kr] = v[j];
  }
  __syncthreads();
#pragma unroll
  for (int t = 0; t < 4; ++t) {
    int s = t * 256 + tid;
    int nr = s >> 4, kc = (s & 15) * 4;
    f16x4 h, l;
#pragma unroll
    for (int j = 0; j < 4; ++j) {
      float q = T[nr][kc + j];
      half_t hh = (half_t)q;
      h[j] = hh;
      l[j] = (half_t)((q - (float)hh) * 2048.0f);
    }
    *(f16x4*)&Wh[(size_t)(n0 + nr) * 2048 + k0 + kc] = h;
    *(f16x4*)&Wl[(size_t)(n0 + nr) * 2048 + k0 + kc] = l;
  }
}

// ---------- projection GEMM (32x32x16 MFMA): C = X @ Wt^T, split-fp16 ----------
// 128x128 tile, BK=32, dbuf LDS, templated MODE (1 = hi-only for V: half LDS/staging).
// Read swizzle: chunk ((ks<<1)|hi) ^ ((r5>>1)&3) on 64B rows -> <=2-way (free).
// C/D layout (m74/m101): col=lane&31, row=(reg&3)+8*(reg>>2)+4*(lane>>5).
#define STAGE_P(nb, kn) do {                                                  \
    _Pragma("unroll")                                                         \
    for (int t_ = 0; t_ < 2; ++t_) {                                          \
      int s_ = t_ * 256 + tid;                                                \
      int row_ = s_ >> 2;                                                     \
      int lch_ = (s_ & 3) ^ ((row_ >> 1) & 3);  /* pre-swizzled source */     \
      size_t ga_ = (size_t)(m0 + row_) * 2048 + (kn) + lch_ * 8;              \
      size_t gb_ = (size_t)(n0 + row_) * 2048 + (kn) + lch_ * 8;              \
      gld16(&Xh[ga_], &sm[nb][s_ * 8]);                                       \
      gld16(&Wh[gb_], &sm[nb][4096 + s_ * 8]);                                \
      if constexpr (MODE == 0) {                                              \
        gld16(&Xl[ga_], &sm[nb][8192 + s_ * 8]);                              \
        gld16(&Wl[gb_], &sm[nb][12288 + s_ * 8]);                             \
      }                                                                       \
    }                                                                         \
  } while (0)

template <int MODE>
__global__ __launch_bounds__(256, MODE == 0 ? 2 : 4) void proj_mfma(
    const half_t* __restrict__ Xh, const half_t* __restrict__ Xl,
    const half_t* __restrict__ Wh, const half_t* __restrict__ Wl,
    half_t* __restrict__ Ch, half_t* __restrict__ Cl) {
  __shared__ half_t sm[2][MODE == 0 ? 16384 : 8192];
  const int tid = threadIdx.x;
  const int lid = blockIdx.x;
  const int swz = (lid & 7) * 128 + (lid >> 3);  // bijective XCD swizzle (1024%8==0)
  const int m0 = (swz >> 4) << 7, n0 = (swz & 15) << 7;
  const int w = tid >> 6, lane = tid & 63, r5 = lane & 31, hi = lane >> 5;
  const int wr = w >> 1, wc = w & 1;
  const int rsw = (r5 >> 1) & 3;
  f32x16 acc0[2][2], accX[2][2];
#pragma unroll
  for (int i = 0; i < 2; ++i)
#pragma unroll
    for (int j = 0; j < 2; ++j) {
#pragma unroll
      for (int r = 0; r < 16; ++r) { acc0[i][j][r] = 0.f; accX[i][j][r] = 0.f; }
    }
  STAGE_P(0, 0);
  __syncthreads();
  for (int k0 = 0; k0 < 2048; k0 += 32) {
    const int buf = (k0 >> 5) & 1;
    if (k0 < 2016) STAGE_P(buf ^ 1, k0 + 32);
#pragma unroll
    for (int ks = 0; ks < 2; ++ks) {
      const int ch = ((ks << 1) | hi) ^ rsw;
      f16x8 a0[2], a1[2], b0[2], b1[2];
#pragma unroll
      for (int i = 0; i < 2; ++i) {
        int ar = wr * 64 + i * 32 + r5;
        int br = wc * 64 + i * 32 + r5;
        a0[i] = *(const f16x8*)&sm[buf][ar * 32 + ch * 8];
        b0[i] = *(const f16x8*)&sm[buf][4096 + br * 32 + ch * 8];
        if constexpr (MODE == 0) {
          a1[i] = *(const f16x8*)&sm[buf][8192 + ar * 32 + ch * 8];
          b1[i] = *(const f16x8*)&sm[buf][12288 + br * 32 + ch * 8];
        }
      }
#pragma unroll
      for (int i = 0; i < 2; ++i)
#pragma unroll
        for (int j = 0; j < 2; ++j) {
          acc0[i][j] = MFMA32(a0[i], b0[j], acc0[i][j], 0, 0, 0);
          if constexpr (MODE == 0) {
            accX[i][j] = MFMA32(a0[i], b1[j], accX[i][j], 0, 0, 0);
            accX[i][j] = MFMA32(a1[i], b0[j], accX[i][j], 0, 0, 0);
          }
        }
    }
    __syncthreads();
  }
#pragma unroll
  for (int i = 0; i < 2; ++i)
#pragma unroll
    for (int j = 0; j < 2; ++j) {
      int mb = m0 + wr * 64 + i * 32 + 4 * hi;
      int n = n0 + wc * 64 + j * 32 + r5;
#pragma unroll
      for (int r = 0; r < 16; ++r) {
        int mrow = mb + (r & 3) + 8 * (r >> 2);
        float q;
        if constexpr (MODE == 0) q = acc0[i][j][r] + accX[i][j][r] * RLO;
        else q = acc0[i][j][r];
        half_t hh = (half_t)q;
        size_t o = (size_t)mrow * 2048 + n;
        Ch[o] = hh;
        if constexpr (MODE == 0) Cl[o] = (half_t)((q - (float)hh) * 2048.0f);
      }
    }
}

// ---------- V[bh][k][d] -> Vt[bh][d][k] ----------
__global__ __launch_bounds__(256) void transpose_v(const half_t* __restrict__ V,
                                                   half_t* __restrict__ Vt) {
  __shared__ half_t T[128 * 128];
  const int tid = threadIdx.x;
  const int bh = blockIdx.y, k0 = blockIdx.x * 128;
  const size_t base = (size_t)bh << 18;
#pragma unroll
  for (int t = 0; t < 8; ++t) {
    int s = t * 256 + tid;
    int kr = s >> 4, ch = s & 15;
    int pc = ch ^ ((kr >> 3) & 15);
    *(f16x8*)&T[kr * 128 + pc * 8] =
        *(const f16x8*)&V[base + (size_t)(k0 + kr) * 128 + ch * 8];
  }
  __syncthreads();
#pragma unroll
  for (int t = 0; t < 8; ++t) {
    int s = t * 256 + tid;
    int d = s >> 4, kc = s & 15;
    f16x8 o;
#pragma unroll
    for (int j = 0; j < 8; ++j) {
      int kr = kc * 8 + j;
      int pc = (d >> 3) ^ (kc & 15);
      o[j] = T[kr * 128 + pc * 8 + (d & 7)];
    }
    *(f16x8*)&Vt[base + (size_t)d * 2048 + k0 + kc * 8] = o;
  }
}

// ---------- column-softmax stats, q-split x4: partial (m,z) per split ----------
// 4 waves x 64 k each (K frags register-persistent); Q staged in dbuf LDS, shared.
// Grid z = q-split (512 q each) -> 2048 blocks total (TLP fix for grid-limited occ).
#define STAGE_Q(nb, qn) do {                                                  \
    int r0_ = tid >> 4, cl0_ = tid & 15;                                      \
    size_t o0_ = base + (size_t)((qn) + r0_) * 128 + ((cl0_ ^ r0_) << 3);     \
    gld16(&Qh[o0_], &sQ0[nb][tid << 3]);                                      \
    gld16(&Ql[o0_], &sQ1[nb][tid << 3]);                                      \
    int r1_ = 16 + r0_;                                                       \
    size_t o1_ = base + (size_t)((qn) + r1_) * 128 + ((cl0_ ^ (r1_ & 15)) << 3); \
    gld16(&Qh[o1_], &sQ0[nb][(256 + tid) << 3]);                              \
    gld16(&Ql[o1_], &sQ1[nb][(256 + tid) << 3]);                              \
  } while (0)

__global__ __launch_bounds__(256, 2) void stats_mfma(
    const half_t* __restrict__ Qh, const half_t* __restrict__ Ql,
    const half_t* __restrict__ Kh, const half_t* __restrict__ Kl,
    float* __restrict__ Mp, float* __restrict__ Zp) {
  __shared__ half_t sQ0[2][4096], sQ1[2][4096];
  const int tid = threadIdx.x;
  const int w = tid >> 6, lane = tid & 63, c = lane & 15, g = lane >> 4;
  const int lid = blockIdx.y * 8 + blockIdx.x;
  const int bh = (lid & 7) * 8 + ((lid >> 3) & 7);   // XCD-swizzled
  const int xb = lid >> 6;
  const int qstart = blockIdx.z << 9;                 // 512 q per split
  const size_t base = (size_t)bh << 18;
  const int kb = xb * 256 + w * 64;
  f32x4 z4 = {0.f, 0.f, 0.f, 0.f};
  f16x8 ka0[4][4], ka1[4][4];
#pragma unroll
  for (int kt = 0; kt < 4; ++kt)
#pragma unroll
    for (int ds = 0; ds < 4; ++ds) {
      size_t a = base + (size_t)(kb + kt * 16 + c) * 128 + ds * 32 + g * 8;
      ka0[kt][ds] = *(const f16x8*)&Kh[a];
      ka1[kt][ds] = *(const f16x8*)&Kl[a];
    }
  float m[4][4], z[4][4];
#pragma unroll
  for (int kt = 0; kt < 4; ++kt)
#pragma unroll
    for (int r = 0; r < 4; ++r) { m[kt][r] = -INFINITY; z[kt][r] = 0.f; }
  STAGE_Q(0, qstart);
  __syncthreads();
  for (int t = 0; t < 16; ++t) {
    const int buf = t & 1;
    if (t < 15) STAGE_Q(buf ^ 1, qstart + ((t + 1) << 5));
#pragma unroll
    for (int qh = 0; qh < 2; ++qh) {
      f16x8 q0v[4], q1v[4];
#pragma unroll
      for (int ds = 0; ds < 4; ++ds) {
        int off = ((qh << 4) | c) * 128 + ((((ds << 2) | g) ^ c) << 3);
        q0v[ds] = *(const f16x8*)&sQ0[buf][off];
        q1v[ds] = *(const f16x8*)&sQ1[buf][off];
      }
#pragma unroll
      for (int kt = 0; kt < 4; ++kt) {
        f32x4 A0 = z4, AX = z4;
#pragma unroll
        for (int ds = 0; ds < 4; ++ds) {
          A0 = MFMA(ka0[kt][ds], q0v[ds], A0, 0, 0, 0);
          AX = MFMA(ka0[kt][ds], q1v[ds], AX, 0, 0, 0);
          AX = MFMA(ka1[kt][ds], q0v[ds], AX, 0, 0, 0);
        }
#pragma unroll
        for (int r = 0; r < 4; ++r) {
          float tt = (A0[r] + AX[r] * RLO) * K1C;
          float mo = m[kt][r];
          float mn = fmaxf(mo, tt);
          float e = __builtin_amdgcn_exp2f(fminf(mo, tt) - mn);
          z[kt][r] = (tt <= mo) ? (z[kt][r] + e) : (z[kt][r] * e + 1.0f);
          m[kt][r] = mn;
        }
      }
    }
    __syncthreads();
  }
#pragma unroll
  for (int mask = 1; mask < 16; mask <<= 1)
#pragma unroll
    for (int kt = 0; kt < 4; ++kt)
#pragma unroll
      for (int r = 0; r < 4; ++r) {
        float mo = __shfl_xor(m[kt][r], mask, 64);
        float zo = __shfl_xor(z[kt][r], mask, 64);
        float mn = fmaxf(m[kt][r], mo);
        z[kt][r] = z[kt][r] * __builtin_amdgcn_exp2f(m[kt][r] - mn) +
                   zo * __builtin_amdgcn_exp2f(mo - mn);
        m[kt][r] = mn;
      }
  if (c == 0) {
    const int pb = (blockIdx.z << 17) + (bh << 11);
#pragma unroll
    for (int kt = 0; kt < 4; ++kt)
#pragma unroll
      for (int r = 0; r < 4; ++r) {
        int idx = pb + kb + kt * 16 + (g << 2) + r;
        Mp[idx] = m[kt][r];
        Zp[idx] = z[kt][r];
      }
  }
}

// ---------- merge 4 q-split partials -> C2 = m* + log2(sum z) ----------
__global__ __launch_bounds__(256) void stats_finalize(const float* __restrict__ Mp,
                                                      const float* __restrict__ Zp,
                                                      float* __restrict__ C2) {
  int i = blockIdx.x * 256 + threadIdx.x;  // 0..131071
  float m = Mp[i], z = Zp[i];
#pragma unroll
  for (int s = 1; s < 4; ++s) {
    float ms = Mp[(s << 17) + i], zs = Zp[(s << 17) + i];
    float mn = fmaxf(m, ms);
    z = z * __builtin_amdgcn_exp2f(m - mn) + zs * __builtin_amdgcn_exp2f(ms - mn);
    m = mn;
  }
  C2[i] = m + __builtin_amdgcn_logf(z);
}

// ---------- attention: 8 waves share dbuf LDS K/V tiles; P=2^(t-C2); O=P@V ----------
#define STAGE_ATTN(nb, ktn) do {                                              \
    int r_ = tid >> 4, chl_ = tid & 15;                                       \
    size_t ro_ = base + (size_t)((ktn) + r_) * 128 + ((chl_ ^ (r_ & 15)) << 3); \
    gld16(&Kh[ro_], &sKh[nb][tid << 3]);                                      \
    gld16(&Kl[ro_], &sKl[nb][tid << 3]);                                      \
    int d_ = tid >> 2, cvl_ = tid & 3;                                        \
    gld16(&Vt[base + (size_t)d_ * 2048 + (ktn) + ((cvl_ ^ ((d_ >> 1) & 3)) << 3)], \
          &sVs[nb][tid << 3]);                                                \
  } while (0)

__global__ __launch_bounds__(512, 4) void attn_mfma(
    const half_t* __restrict__ Qh, const half_t* __restrict__ Ql,
    const half_t* __restrict__ Kh, const half_t* __restrict__ Kl,
    const half_t* __restrict__ Vt, const float* __restrict__ C2,
    float* __restrict__ O) {
  __shared__ half_t sKh[2][4096], sKl[2][4096], sVs[2][4096];
  __shared__ half_t sP[8][16][40];
  __shared__ float sC2[2048];
  const int tid = threadIdx.x;
  const int w = tid >> 6, lane = tid & 63, c = lane & 15, g = lane >> 4;
  const int lid = blockIdx.y * 16 + blockIdx.x;
  const int bh = (lid & 7) * 8 + ((lid >> 3) & 7);   // XCD-swizzled
  const int qx = lid >> 6;
  const size_t base = (size_t)bh << 18;
  const int qb = qx * 128 + w * 16;
  f32x4 z4 = {0.f, 0.f, 0.f, 0.f};
  f16x8 qf0[4], qf1[4];
#pragma unroll
  for (int ds = 0; ds < 4; ++ds) {
    size_t a = base + (size_t)(qb + c) * 128 + ds * 32 + g * 8;
    qf0[ds] = *(const f16x8*)&Qh[a];
    qf1[ds] = *(const f16x8*)&Ql[a];
  }
  f32x4 Oacc[8];
#pragma unroll
  for (int dt = 0; dt < 8; ++dt) Oacc[dt] = z4;
  ((f32x4*)sC2)[tid] = ((const f32x4*)(C2 + ((size_t)bh << 11)))[tid];
  STAGE_ATTN(0, 0);
  __syncthreads();
  for (int t = 0; t < 64; ++t) {
    const int buf = t & 1;
    const int kt = t << 5;
    if (t < 63) STAGE_ATTN(buf ^ 1, kt + 32);
#pragma unroll
    for (int h = 0; h < 2; ++h) {
      f32x4 A0 = z4, AX = z4;
#pragma unroll
      for (int ds = 0; ds < 4; ++ds) {
        int off = ((h << 4) | c) * 128 + ((((ds << 2) | g) ^ c) << 3);
        f16x8 k0v = *(const f16x8*)&sKh[buf][off];
        f16x8 k1v = *(const f16x8*)&sKl[buf][off];
        A0 = MFMA(k0v, qf0[ds], A0, 0, 0, 0);
        AX = MFMA(k0v, qf1[ds], AX, 0, 0, 0);
        AX = MFMA(k1v, qf0[ds], AX, 0, 0, 0);
      }
      f32x4 c2v = *(const f32x4*)&sC2[kt + (h << 4) + (g << 2)];
      f16x4 pv;
#pragma unroll
      for (int r = 0; r < 4; ++r)
        pv[r] = (half_t)__builtin_amdgcn_exp2f((A0[r] + AX[r] * RLO) * K1C - c2v[r]);
      *(f16x4*)&sP[w][c][(h << 4) + (g << 2)] = pv;
    }
    f16x8 pa = *(const f16x8*)&sP[w][c][g << 3];
#pragma unroll
    for (int dt = 0; dt < 8; ++dt) {
      int dd = (dt << 4) + c;
      f16x8 vb = *(const f16x8*)&sVs[buf][dd * 32 + ((g ^ ((dd >> 1) & 3)) << 3)];
      Oacc[dt] = MFMA(pa, vb, Oacc[dt], 0, 0, 0);
    }
    __syncthreads();
  }
#pragma unroll
  for (int dt = 0; dt < 8; ++dt)
#pragma unroll
    for (int r = 0; r < 4; ++r)
      O[base + (size_t)(qb + (g << 2) + r) * 128 + (dt << 4) + c] = Oacc[dt][r];
}

extern "C" void kernel_launch(void* const* d_in, const int* in_sizes, int n_in,
                              void* d_out, int out_size, void* d_ws, size_t ws_size,
                              hipStream_t stream) {
  (void)in_sizes; (void)n_in; (void)out_size; (void)ws_size;
  const float* x = (const float*)d_in[0];
  const float* wq = (const float*)d_in[1];
  const float* wk = (const float*)d_in[2];
  const float* wv = (const float*)d_in[3];
  float* out = (float*)d_out;
  char* ws = (char*)d_ws;
  const size_t S2 = 33554432;  // bytes of one fp16 split [8192][2048]
  half_t* Wth = (half_t*)ws;
  half_t* Wtl = (half_t*)(ws + 8388608);
  half_t* Qh = (half_t*)(ws + 16777216);
  half_t* Ql = (half_t*)(ws + 16777216 + S2);
  half_t* Kh = (half_t*)(ws + 16777216 + 2 * S2);
  half_t* Kl = (half_t*)(ws + 16777216 + 3 * S2);
  half_t* Vh = (half_t*)(ws + 16777216 + 4 * S2);
  half_t* Vth = (half_t*)(ws + 16777216 + 5 * S2);
  float* C2 = (float*)(ws + 16777216 + 6 * S2);
  float* Mp = C2 + 131072;       // 4 x 64 x 2048 partial maxes (2 MB)
  float* Zp = Mp + 524288;       // 4 x 64 x 2048 partial sums  (2 MB)
  half_t* Xh = (half_t*)d_out;
  half_t* Xl = (half_t*)((char*)d_out + S2);
  dim3 b(256);
  split_x<<<2048, b, 0, stream>>>(x, Xh, Xl);
  wtrans_split<<<dim3(32, 32), b, 0, stream>>>(wq, Wth, Wtl);
  proj_mfma<0><<<dim3(1024), b, 0, stream>>>(Xh, Xl, Wth, Wtl, Qh, Ql);
  wtrans_split<<<dim3(32, 32), b, 0, stream>>>(wk, Wth, Wtl);
  proj_mfma<0><<<dim3(1024), b, 0, stream>>>(Xh, Xl, Wth, Wtl, Kh, Kl);
  wtrans_split<<<dim3(32, 32), b, 0, stream>>>(wv, Wth, Wtl);
  proj_mfma<1><<<dim3(1024), b, 0, stream>>>(Xh, Xl, Wth, Wtl, Vh, nullptr);
  transpose_v<<<dim3(16, 64), b, 0, stream>>>(Vh, Vth);
  stats_mfma<<<dim3(8, 64, 4), b, 0, stream>>>(Qh, Ql, Kh, Kl, Mp, Zp);
  stats_finalize<<<dim3(512), b, 0, stream>>>(Mp, Zp, C2);
  attn_mfma<<<dim3(16, 64), dim3(512), 0, stream>>>(Qh, Ql, Kh, Kl, Vth, C2, out);
}